// Round 6
// baseline (936.527 us; speedup 1.0000x reference)
//
#include <hip/hip_runtime.h>
#include <math.h>

// DASCO forward, round 6: (R5) + fully fused attention adjacency. Scores are
// never materialized: pass1 computes per-head softmax denominators (recompute
// scores, exp, row-reduce), pass2 recomputes scores and writes the head-mean
// softmax adjacency directly (diag=1, row/col masks). Key trick: head h's
// k-slice offset is 96h+32(ks%3)=32ks, so staging is a plain K=768 loop with
// accumulator reset every 3 k-steps. B=32, S=512, D=768, M=384.

typedef __bf16 bf16x8 __attribute__((ext_vector_type(8)));
typedef __bf16 bf16x4 __attribute__((ext_vector_type(4)));
typedef float f32x4 __attribute__((ext_vector_type(4)));

__device__ __forceinline__ void glds16(const void* g, void* l) {
    __builtin_amdgcn_global_load_lds(
        (const __attribute__((address_space(1))) unsigned*)g,
        (__attribute__((address_space(3))) unsigned*)l, 16, 0, 0);
}

__device__ __forceinline__ float sigf(float x) { return 1.f / (1.f + __expf(-x)); }

// ---------------- bf16 MFMA GEMM, 128x128 tile, dbuf, m-innermost grid --------
// C[z][m][n] = sum_k A[z][m][k]*B[z][n][k] (+bias), act: 0 none; 1 relu; 2 elu;
// 3 gcn-combine(E=Isem); 4 relu+gate(E=Hold). Writes masked to n < nMax.
__global__ __launch_bounds__(256) void mfma_gemm(
    const __bf16* __restrict__ A, const __bf16* __restrict__ B,
    const float* __restrict__ bias, const float* __restrict__ E,
    float* __restrict__ Cf, __bf16* __restrict__ Cb,
    int K, int lda, int ldb, int ldc, int nMax,
    long sAo, long sAi, long sBo, long sBi, int zInner, long sC, int act)
{
    __shared__ __bf16 As[2][128 * 32];
    __shared__ __bf16 Bs[2][128 * 32];
    int z = blockIdx.z;
    long aBase = (long)(z / zInner) * sAo + (long)(z % zInner) * sAi;
    long bBase = (long)(z / zInner) * sBo + (long)(z % zInner) * sBi;
    long cBase = (long)z * sC;
    int m0 = blockIdx.x * 128, n0 = blockIdx.y * 128;
    int tid = threadIdx.x;
    int wave = tid >> 6, lane = tid & 63;
    int wm = wave >> 1, wn = wave & 1;

    int e0 = tid, e1 = tid + 256;
    const __bf16* Ag0 = A + aBase + (long)(m0 + (e0 >> 2)) * lda + (e0 & 3) * 8;
    const __bf16* Ag1 = A + aBase + (long)(m0 + (e1 >> 2)) * lda + (e1 & 3) * 8;
    const __bf16* Bg0 = B + bBase + (long)(n0 + (e0 >> 2)) * ldb + (e0 & 3) * 8;
    const __bf16* Bg1 = B + bBase + (long)(n0 + (e1 >> 2)) * ldb + (e1 & 3) * 8;

    f32x4 acc[4][4];
#pragma unroll
    for (int i = 0; i < 4; i++)
#pragma unroll
        for (int j = 0; j < 4; j++) acc[i][j] = (f32x4){0.f, 0.f, 0.f, 0.f};

    int arow = wm * 64 + (lane & 15);
    int brow = wn * 64 + (lane & 15);
    int quad = lane >> 4;

    glds16(Ag0, As[0] + e0 * 8); glds16(Ag1, As[0] + e1 * 8);
    glds16(Bg0, Bs[0] + e0 * 8); glds16(Bg1, Bs[0] + e1 * 8);

    int cur = 0;
    for (int k0 = 0; k0 < K; k0 += 32) {
        __syncthreads();
        if (k0 + 32 < K) {
            int nk = k0 + 32, nb = cur ^ 1;
            glds16(Ag0 + nk, As[nb] + e0 * 8); glds16(Ag1 + nk, As[nb] + e1 * 8);
            glds16(Bg0 + nk, Bs[nb] + e0 * 8); glds16(Bg1 + nk, Bs[nb] + e1 * 8);
        }
        const bf16x8* Asv = (const bf16x8*)As[cur];
        const bf16x8* Bsv = (const bf16x8*)Bs[cur];
        bf16x8 af[4], bfr[4];
#pragma unroll
        for (int mi = 0; mi < 4; mi++) af[mi] = Asv[(arow + mi * 16) * 4 + quad];
#pragma unroll
        for (int ni = 0; ni < 4; ni++) bfr[ni] = Bsv[(brow + ni * 16) * 4 + quad];
#pragma unroll
        for (int mi = 0; mi < 4; mi++)
#pragma unroll
            for (int ni = 0; ni < 4; ni++)
                acc[mi][ni] = __builtin_amdgcn_mfma_f32_16x16x32_bf16(
                    af[mi], bfr[ni], acc[mi][ni], 0, 0, 0);
        cur ^= 1;
    }

    int crow = m0 + wm * 64 + (lane >> 4) * 4;
    int ccol = n0 + wn * 64 + (lane & 15);
    float bv[4];
#pragma unroll
    for (int ni = 0; ni < 4; ni++) {
        int col = ccol + ni * 16;
        bv[ni] = (bias && col < nMax) ? bias[col] : 0.f;
    }
#pragma unroll
    for (int mi = 0; mi < 4; mi++) {
#pragma unroll
        for (int ni = 0; ni < 4; ni++) {
            int col = ccol + ni * 16;
            if (col >= nMax) continue;
#pragma unroll
            for (int r = 0; r < 4; r++) {
                float v = acc[mi][ni][r] + bv[ni];
                long idx = cBase + (long)(crow + mi * 16 + r) * ldc + col;
                if (act == 1) v = fmaxf(v, 0.f);
                else if (act == 2) v = (v > 0.f) ? v : expm1f(v);
                else if (act == 3) { float e = E[idx]; float g = 0.6f * sigf(v); v = (1.f - g) * e + g * v; }
                else if (act == 4) { float e = E[idx]; v = fmaxf(v, 0.f); float g = sigf(e); v = g * v + (1.f - g) * e; }
                if (Cf) Cf[idx] = v;
                if (Cb) Cb[idx] = (__bf16)v;
            }
        }
    }
}

// ---------------- fused attention adjacency (2 passes, no score tensor) -------
// qk: [16384][1536] bf16 (q cols 0..768, k cols 768..1536). Per block:
// (t-tile=blockIdx.x, s-tile=blockIdx.y, b=z). 24 k-steps, acc reset per head.
// mode 0: lpart[((b*8+h)*8 + tb*2+wn)][512] = per-col-half row sums of exp.
// mode 1: adj[b,s,t] = rowmask*(t==s ? 1 : cmask*(1/8)Σ_h linv_h(s)·exp).
__global__ __launch_bounds__(256) void attn_pass(
    const __bf16* __restrict__ qk, const int* __restrict__ attn_mask,
    const float* __restrict__ linv_g, float* __restrict__ lpart,
    __bf16* __restrict__ adj, int mode)
{
    const int S = 512;
    __shared__ __bf16 As[2][128 * 32];
    __shared__ __bf16 Bs[2][128 * 32];
    __shared__ float linvs[8][128];
    int b = blockIdx.z;
    int t0 = blockIdx.x * 128, s0 = blockIdx.y * 128;
    int tid = threadIdx.x;
    int wave = tid >> 6, lane = tid & 63;
    int wm = wave >> 1, wn = wave & 1;
    int quad = lane >> 4, l16 = lane & 15;

    long qBase = (long)b * S * 1536;
    int e0 = tid, e1 = tid + 256;
    const __bf16* Ag0 = qk + qBase + (long)(s0 + (e0 >> 2)) * 1536 + (e0 & 3) * 8;
    const __bf16* Ag1 = qk + qBase + (long)(s0 + (e1 >> 2)) * 1536 + (e1 & 3) * 8;
    const __bf16* Bg0 = qk + qBase + (long)(t0 + (e0 >> 2)) * 1536 + 768 + (e0 & 3) * 8;
    const __bf16* Bg1 = qk + qBase + (long)(t0 + (e1 >> 2)) * 1536 + 768 + (e1 & 3) * 8;

    if (mode) {
        for (int i = tid; i < 1024; i += 256) {
            int h = i >> 7, r = i & 127;
            linvs[h][r] = linv_g[((long)b * 8 + h) * S + s0 + r];
        }
    }
    float cmask[4];
#pragma unroll
    for (int ni = 0; ni < 4; ni++)
        cmask[ni] = attn_mask[b * S + t0 + wn * 64 + ni * 16 + l16] ? 1.f : 0.f;

    const float scale = 0.1020620726159658f;  // 1/sqrt(96)
    int arow = wm * 64 + l16;
    int brow = wn * 64 + l16;

    f32x4 acc[4][4];
    float outacc[4][4][4];
#pragma unroll
    for (int i = 0; i < 4; i++)
#pragma unroll
        for (int j = 0; j < 4; j++) {
            acc[i][j] = (f32x4){0.f, 0.f, 0.f, 0.f};
#pragma unroll
            for (int r = 0; r < 4; r++) outacc[i][j][r] = 0.f;
        }

    glds16(Ag0, As[0] + e0 * 8); glds16(Ag1, As[0] + e1 * 8);
    glds16(Bg0, Bs[0] + e0 * 8); glds16(Bg1, Bs[0] + e1 * 8);

    int cur = 0;
    for (int ks = 0; ks < 24; ks++) {
        __syncthreads();
        if (ks + 1 < 24) {
            int nk = (ks + 1) * 32, nb = cur ^ 1;
            glds16(Ag0 + nk, As[nb] + e0 * 8); glds16(Ag1 + nk, As[nb] + e1 * 8);
            glds16(Bg0 + nk, Bs[nb] + e0 * 8); glds16(Bg1 + nk, Bs[nb] + e1 * 8);
        }
        const bf16x8* Asv = (const bf16x8*)As[cur];
        const bf16x8* Bsv = (const bf16x8*)Bs[cur];
        bf16x8 af[4], bfr[4];
#pragma unroll
        for (int mi = 0; mi < 4; mi++) af[mi] = Asv[(arow + mi * 16) * 4 + quad];
#pragma unroll
        for (int ni = 0; ni < 4; ni++) bfr[ni] = Bsv[(brow + ni * 16) * 4 + quad];
#pragma unroll
        for (int mi = 0; mi < 4; mi++)
#pragma unroll
            for (int ni = 0; ni < 4; ni++)
                acc[mi][ni] = __builtin_amdgcn_mfma_f32_16x16x32_bf16(
                    af[mi], bfr[ni], acc[mi][ni], 0, 0, 0);
        cur ^= 1;

        if (ks % 3 == 2) {           // head boundary: epilogue + reset
            int h = ks / 3;
            if (mode == 0) {
#pragma unroll
                for (int mi = 0; mi < 4; mi++) {
                    float rsum[4] = {0.f, 0.f, 0.f, 0.f};
#pragma unroll
                    for (int ni = 0; ni < 4; ni++)
#pragma unroll
                        for (int r = 0; r < 4; r++)
                            rsum[r] += cmask[ni] * __expf(acc[mi][ni][r] * scale);
#pragma unroll
                    for (int r = 0; r < 4; r++) {
                        float v = rsum[r];
                        v += __shfl_xor(v, 1); v += __shfl_xor(v, 2);
                        v += __shfl_xor(v, 4); v += __shfl_xor(v, 8);
                        if (l16 == 0) {
                            int row = wm * 64 + mi * 16 + quad * 4 + r;
                            lpart[(((long)(b * 8 + h) * 4 + blockIdx.x) * 2 + wn) * S
                                  + s0 + row] = v;
                        }
                    }
                }
            } else {
                float lv[4][4];
#pragma unroll
                for (int mi = 0; mi < 4; mi++)
#pragma unroll
                    for (int r = 0; r < 4; r++)
                        lv[mi][r] = linvs[h][wm * 64 + mi * 16 + quad * 4 + r];
#pragma unroll
                for (int mi = 0; mi < 4; mi++)
#pragma unroll
                    for (int ni = 0; ni < 4; ni++)
#pragma unroll
                        for (int r = 0; r < 4; r++)
                            outacc[mi][ni][r] += lv[mi][r] * __expf(acc[mi][ni][r] * scale);
            }
#pragma unroll
            for (int i = 0; i < 4; i++)
#pragma unroll
                for (int j = 0; j < 4; j++) acc[i][j] = (f32x4){0.f, 0.f, 0.f, 0.f};
        }
    }

    if (mode) {
        float rmask[4][4];
#pragma unroll
        for (int mi = 0; mi < 4; mi++)
#pragma unroll
            for (int r = 0; r < 4; r++)
                rmask[mi][r] = attn_mask[b * S + s0 + wm * 64 + mi * 16 + quad * 4 + r] ? 1.f : 0.f;
#pragma unroll
        for (int mi = 0; mi < 4; mi++) {
#pragma unroll
            for (int ni = 0; ni < 4; ni++) {
                int col = t0 + wn * 64 + ni * 16 + l16;
#pragma unroll
                for (int r = 0; r < 4; r++) {
                    int row = s0 + wm * 64 + mi * 16 + quad * 4 + r;
                    float v = (col == row) ? 1.f : cmask[ni] * outacc[mi][ni][r] * 0.125f;
                    adj[(long)b * S * S + (long)row * S + col] = (__bf16)(rmask[mi][r] * v);
                }
            }
        }
    }
}

// linv = 1/max(sum of 8 partials, 1e-30)
__global__ void linv_reduce(const float* __restrict__ lpart, float* __restrict__ linv_g)
{
    long i = (long)blockIdx.x * 256 + threadIdx.x;  // 32*8*512
    int s = i & 511;
    long bh = i >> 9;
    float sum = 0.f;
#pragma unroll
    for (int j = 0; j < 8; j++) sum += lpart[(bh * 8 + j) * 512 + s];
    linv_g[i] = 1.f / fmaxf(sum, 1e-30f);
}

// ---------------- casts ----------------
__global__ void cast_bf16_kernel(const float* __restrict__ in, __bf16* __restrict__ out, long n4)
{
    long i = (long)blockIdx.x * blockDim.x + threadIdx.x;
    if (i < n4) {
        float4 v = ((const float4*)in)[i];
        bf16x4 o; o[0] = (__bf16)v.x; o[1] = (__bf16)v.y; o[2] = (__bf16)v.z; o[3] = (__bf16)v.w;
        ((bf16x4*)out)[i] = o;
    }
}

__global__ __launch_bounds__(256) void castT_kernel(
    const float* __restrict__ in, __bf16* __restrict__ out, int R, int C)
{
    __shared__ float t[32][33];
    long zo = (long)blockIdx.z * R * C;
    int r0 = blockIdx.y * 32, c0 = blockIdx.x * 32;
    int tid = threadIdx.x;
    int r = tid >> 3, c4 = (tid & 7) * 4;
    float4 v = *(const float4*)(in + zo + (long)(r0 + r) * C + c0 + c4);
    t[r][c4] = v.x; t[r][c4 + 1] = v.y; t[r][c4 + 2] = v.z; t[r][c4 + 3] = v.w;
    __syncthreads();
    int c = tid >> 3, r4 = (tid & 7) * 4;
    bf16x4 o;
    o[0] = (__bf16)t[r4 + 0][c]; o[1] = (__bf16)t[r4 + 1][c];
    o[2] = (__bf16)t[r4 + 2][c]; o[3] = (__bf16)t[r4 + 3][c];
    *(bf16x4*)(out + zo + (long)(c0 + c) * R + r0 + r4) = o;
}

// ---------------- row L2-normalize + bf16 copy ----------------
__global__ __launch_bounds__(128) void rownorm(
    const float* __restrict__ h1, const float* __restrict__ h2,
    __bf16* __restrict__ h1b, __bf16* __restrict__ h2b, int Dm)
{
    const float* p = (blockIdx.y ? h2 : h1) + (long)blockIdx.x * Dm;
    __bf16* pb = (blockIdx.y ? h2b : h1b) + (long)blockIdx.x * Dm;
    int tid = threadIdx.x;
    float ss = 0.f;
    for (int i = tid; i < Dm; i += 128) { float v = p[i]; ss += v * v; }
    for (int o = 32; o > 0; o >>= 1) ss += __shfl_down(ss, o);
    __shared__ float sb[2];
    __shared__ float scale;
    if ((tid & 63) == 0) sb[tid >> 6] = ss;
    __syncthreads();
    if (tid == 0) scale = 1.f / fmaxf(sqrtf(sb[0] + sb[1]), 1e-12f);
    __syncthreads();
    for (int i = tid; i < Dm; i += 128) pb[i] = (__bf16)(p[i] * scale);
}

// ---------------- fused symmetric scope loss per (b,s) row (bf16 G) -----------
__global__ __launch_bounds__(256) void loss_kernel(
    const __bf16* __restrict__ G11, const __bf16* __restrict__ G12,
    const __bf16* __restrict__ G21, const __bf16* __restrict__ G22,
    const int* __restrict__ s_mask, const int* __restrict__ a_mask,
    float* __restrict__ lossb)
{
    const int S = 512;
    int s = blockIdx.x, b = blockIdx.y;
    int tid = threadIdx.x;
    if (a_mask[b * S + s] == 0) {
        if (tid == 0) lossb[b * S + s] = 0.f;
        return;
    }
    long base = ((long)b * S + s) * S;
    const float it = 1.f / 0.07f;
    float sms = s_mask[b * S + s] ? 1.f : 0.f;
    float d12 = (float)G12[base + s], d21 = (float)G21[base + s];
    float w1i = sms * d12 * it, w2i = sms * d21 * it;
    float p[8];
#pragma unroll
    for (int h = 0; h < 8; h++) p[h] = 0.f;
#pragma unroll
    for (int j = 0; j < 2; j++) {
        int t = tid + j * 256;
        bool smt = s_mask[b * S + t] != 0;
        bool off = (t != s);
        float g11 = (float)G11[base + t], g12 = (float)G12[base + t];
        float g21 = (float)G21[base + t], g22 = (float)G22[base + t];
        float e11 = __expf(g11 * it), e12 = __expf(g12 * it);
        float e21 = __expf(g21 * it), e22 = __expf(g22 * it);
        p[2] += e11; p[3] += e12; p[6] += e22; p[7] += e21;
        if (off) {
            p[0] += smt ? e11 : 1.f;
            p[4] += smt ? e22 : 1.f;
            p[1] += smt ? __expf(g12 * w1i) : 1.f;
            p[5] += smt ? __expf(g21 * w2i) : 1.f;
        }
    }
    __shared__ float red[4][8];
    int lane = tid & 63, w = tid >> 6;
#pragma unroll
    for (int h = 0; h < 8; h++) {
        float v = p[h];
        for (int o = 32; o > 0; o >>= 1) v += __shfl_down(v, o);
        if (lane == 0) red[w][h] = v;
    }
    __syncthreads();
    if (tid == 0) {
        float r[8];
#pragma unroll
        for (int h = 0; h < 8; h++) r[h] = red[0][h] + red[1][h] + red[2][h] + red[3][h];
        float g11ss = (float)G11[base + s], g22ss = (float)G22[base + s];
        float pos1 = __expf(w1i) + r[0] + r[1];
        float alle1 = r[2] - __expf(g11ss * it) + r[3];
        float pos2 = __expf(w2i) + r[4] + r[5];
        float alle2 = r[6] - __expf(g22ss * it) + r[7];
        lossb[b * S + s] = 0.5f * ((__logf(alle1) - __logf(pos1)) +
                                   (__logf(alle2) - __logf(pos2)));
    }
}

__global__ __launch_bounds__(256) void final_reduce(
    const float* __restrict__ lossb, float* __restrict__ out, int n)
{
    int tid = threadIdx.x;
    float s = 0.f;
    for (int i = tid; i < n; i += 256) s += lossb[i];
    for (int o = 32; o > 0; o >>= 1) s += __shfl_down(s, o);
    __shared__ float sb[4];
    if ((tid & 63) == 0) sb[tid >> 6] = s;
    __syncthreads();
    if (tid == 0) out[0] = (sb[0] + sb[1] + sb[2] + sb[3]) / (float)n;
}

// ---------------- host ----------------
static inline void mg(hipStream_t st, const __bf16* A, const __bf16* B, const float* bias,
                      const float* E, float* Cf, __bf16* Cb,
                      int M, int Npad, int nMax, int K, int lda, int ldb, int ldc,
                      long sAo, long sAi, long sBo, long sBi, int zInner, long sC, int nz,
                      int act)
{
    dim3 g(M / 128, Npad / 128, nz);
    mfma_gemm<<<g, 256, 0, st>>>(A, B, bias, E, Cf, Cb, K, lda, ldb, ldc, nMax,
                                 sAo, sAi, sBo, sBi, zInner, sC, act);
}

static inline void castT(hipStream_t st, const float* in, __bf16* out, int R, int C, int nz)
{
    castT_kernel<<<dim3(C / 32, R / 32, nz), 256, 0, st>>>(in, out, R, C);
}

extern "C" void kernel_launch(void* const* d_in, const int* in_sizes, int n_in,
                              void* d_out, int out_size, void* d_ws, size_t ws_size,
                              hipStream_t stream)
{
    const int B = 32, S = 512, D = 768, Mm = 384;
    const int MT = B * S;  // 16384
    const float* X    = (const float*)d_in[0];
    const float* adjm = (const float*)d_in[1];
    const int* attn_mask = (const int*)d_in[2];
    const int* s_mask    = (const int*)d_in[3];
    const int* a_mask    = (const int*)d_in[4];
    const float* Wq = (const float*)d_in[5],  *bq = (const float*)d_in[6];
    const float* Wk = (const float*)d_in[7],  *bk = (const float*)d_in[8];
    const float* semW0 = (const float*)d_in[9],  *semb0 = (const float*)d_in[10];
    const float* semW1 = (const float*)d_in[11], *semb1 = (const float*)d_in[12];
    const float* depW0 = (const float*)d_in[13], *depb0 = (const float*)d_in[14];
    const float* depW1 = (const float*)d_in[15], *depb1 = (const float*)d_in[16];
    const float* fc1W = (const float*)d_in[17], *fc1b = (const float*)d_in[18];
    const float* fc2W = (const float*)d_in[19], *fc2b = (const float*)d_in[20];
    const float* fc3W = (const float*)d_in[21], *fc3b = (const float*)d_in[22];
    const float* fc4W = (const float*)d_in[23], *fc4b = (const float*)d_in[24];

    char* ws = (char*)d_ws;
    const size_t MB = 1u << 20;
    const size_t KB = 1u << 10;

    // rotating regions
    __bf16* Xb      = (__bf16*)(ws + 0 * MB);     // 24MB
    __bf16* adj_agb = (__bf16*)(ws + 24 * MB);    // 16MB \ contiguous
    __bf16* adjmb   = (__bf16*)(ws + 40 * MB);    // 16MB /
    __bf16* qkb     = (__bf16*)(ws + 56 * MB);    // 48MB [16384][1536] (attn)
    float*  lpart   = (float*)(ws + 104 * MB);    // 8MB (attn only)
    float*  linv    = (float*)(ws + 112 * MB);    // 512KB (attn only)
    __bf16* P64     = (__bf16*)(ws + 56 * MB);    // 24MB [64][384][512] (layers)
    float*  Isem    = (float*)(ws + 82 * MB);     // 24MB
    __bf16* Icomb   = (__bf16*)(ws + 106 * MB);   // 12MB
    float*  H       = (float*)(ws + 118 * MB);    // 24MB
    __bf16* Hb      = (__bf16*)(ws + 142 * MB);   // 12MB (l0 out; rewritten l1)
    __bf16* Isemb   = (__bf16*)(ws + 154 * MB);   // 12MB
    __bf16* t1b     = (__bf16*)(ws + 0 * MB);     // 1MB (proj; Xb dead)
    float*  h1      = (float*)(ws + 4 * MB);      // 24MB (adj regions dead)
    float*  h2      = (float*)(ws + 28 * MB);     // 24MB
    __bf16* h1b     = (__bf16*)(ws + 56 * MB);    // 12MB \ contiguous (P64 dead)
    __bf16* h2b     = (__bf16*)(ws + 68 * MB);    // 12MB /
    __bf16* G11     = (__bf16*)(ws + 80 * MB);    // 16MB x4 contiguous
    __bf16* G12     = (__bf16*)(ws + 96 * MB);
    __bf16* G21     = (__bf16*)(ws + 112 * MB);
    __bf16* G22     = (__bf16*)(ws + 128 * MB);   // ends 144MB

    // permanent weights @168MB
    char* wreg = ws + 168 * MB;
    __bf16* WqkT   = (__bf16*)(wreg + 0 * KB);     // [1536][768] 2304KB
    __bf16* semW0T = (__bf16*)(wreg + 2304 * KB);  // 576KB \ contiguous
    __bf16* depW0T = (__bf16*)(wreg + 2880 * KB);  // 576KB /
    __bf16* fc4WT  = (__bf16*)(wreg + 3456 * KB);  // 576KB
    __bf16* semW1T = (__bf16*)(wreg + 4032 * KB);  // 288KB \ contiguous
    __bf16* depW1T = (__bf16*)(wreg + 4320 * KB);  // 288KB /
    __bf16* fc3WT  = (__bf16*)(wreg + 4608 * KB);  // 288KB
    __bf16* fc1WT  = (__bf16*)(wreg + 4896 * KB);  // [128 pad][384] 96KB
    __bf16* fc2WT  = (__bf16*)(wreg + 4992 * KB);  // [384][32] 24KB
    float*  bqk    = (float*)(wreg + 5016 * KB);   // [1536]
    float*  lossb  = (float*)(wreg + 5032 * KB);   // 64KB

    long nSD = (long)S * D, nSM = (long)S * Mm, nSS = (long)S * S;
    long nPM = (long)Mm * S;

    // ---- casts ----
    cast_bf16_kernel<<<(MT * D / 4 + 255) / 256, 256, 0, stream>>>(X, Xb, (long)MT * D / 4);
    cast_bf16_kernel<<<((long)B * nSS / 4 + 255) / 256, 256, 0, stream>>>(adjm, adjmb, (long)B * nSS / 4);
    castT(stream, Wq, WqkT, D, D, 1);
    castT(stream, Wk, WqkT + (long)D * D, D, D, 1);
    castT(stream, semW0, semW0T, D, Mm, 1);
    castT(stream, depW0, depW0T, D, Mm, 1);
    castT(stream, fc4W, fc4WT, D, Mm, 1);
    castT(stream, semW1, semW1T, Mm, Mm, 1);
    castT(stream, depW1, depW1T, Mm, Mm, 1);
    castT(stream, fc3W, fc3WT, Mm, Mm, 1);
    castT(stream, fc1W, fc1WT, Mm, 32, 1);
    hipMemsetAsync(fc1WT + 32 * Mm, 0, (size_t)96 * Mm * 2, stream);
    castT(stream, fc2W, fc2WT, 32, Mm, 1);
    hipMemcpyAsync(bqk, bq, D * 4, hipMemcpyDeviceToDevice, stream);
    hipMemcpyAsync(bqk + D, bk, D * 4, hipMemcpyDeviceToDevice, stream);

    // ---- fused q|k projection ----
    mg(stream, Xb, WqkT, bqk, nullptr, nullptr, qkb, MT, 1536, 1536, D,
       D, D, 1536, 0, 0, 0, 0, 1, 0, 1, 0);

    // ---- fused attention adjacency (no score tensor) ----
    attn_pass<<<dim3(4, 4, B), 256, 0, stream>>>(qkb, attn_mask, nullptr, lpart, nullptr, 0);
    linv_reduce<<<(B * 8 * S) / 256, 256, 0, stream>>>(lpart, linv);
    attn_pass<<<dim3(4, 4, B), 256, 0, stream>>>(qkb, attn_mask, linv, nullptr, adj_agb, 1);

    // ---- layer 0 (reassociated) ----
    mg(stream, semW0T, Xb, nullptr, nullptr, nullptr, P64, Mm, S, S, D,
       D, D, S, (long)Mm * D, 0, 0, nSD, 32, nPM, 64, 0);
    mg(stream, adj_agb, P64, semb0, nullptr, Isem, nullptr, S, Mm, Mm, S,
       S, S, Mm, 0, nSS, 0, nPM, 32, nSM, 32, 0);
    mg(stream, adjmb, P64 + 32 * nPM, depb0, Isem, nullptr, Icomb, S, Mm, Mm, S,
       S, S, Mm, 0, nSS, 0, nPM, 32, nSM, 32, 3);
    mg(stream, Xb, fc4WT, fc4b, nullptr, H, nullptr, MT, Mm, Mm, D,
       D, D, Mm, 0, 0, 0, 0, 1, 0, 1, 0);
    mg(stream, Icomb, fc3WT, fc3b, H, H, Hb, MT, Mm, Mm, Mm,
       Mm, Mm, Mm, 0, 0, 0, 0, 1, 0, 1, 4);

    // ---- layer 1 (reassociated) ----
    mg(stream, semW1T, Hb, nullptr, nullptr, nullptr, P64, Mm, S, S, Mm,
       Mm, Mm, S, (long)Mm * Mm, 0, 0, nSM, 32, nPM, 64, 0);
    mg(stream, adj_agb, P64, semb1, nullptr, Isem, Isemb, S, Mm, Mm, S,
       S, S, Mm, 0, nSS, 0, nPM, 32, nSM, 32, 0);
    mg(stream, adjmb, P64 + 32 * nPM, depb1, Isem, nullptr, Icomb, S, Mm, Mm, S,
       S, S, Mm, 0, nSS, 0, nPM, 32, nSM, 32, 3);
    mg(stream, Icomb, fc3WT, fc3b, H, nullptr, Hb, MT, Mm, Mm, Mm,
       Mm, Mm, Mm, 0, 0, 0, 0, 1, 0, 1, 4);

    // ---- projection heads ----
    mg(stream, Hb, fc1WT, fc1b, nullptr, nullptr, t1b, MT, 128, 32, Mm,
       Mm, Mm, 32, 0, 0, 0, 0, 1, 0, 1, 2);
    mg(stream, t1b, fc2WT, fc2b, nullptr, h1, nullptr, MT, Mm, Mm, 32,
       32, 32, Mm, 0, 0, 0, 0, 1, 0, 1, 0);
    mg(stream, Isemb, fc1WT, fc1b, nullptr, nullptr, t1b, MT, 128, 32, Mm,
       Mm, Mm, 32, 0, 0, 0, 0, 1, 0, 1, 2);
    mg(stream, t1b, fc2WT, fc2b, nullptr, h2, nullptr, MT, Mm, Mm, 32,
       32, 32, Mm, 0, 0, 0, 0, 1, 0, 1, 0);

    rownorm<<<dim3(MT, 2), 128, 0, stream>>>(h1, h2, h1b, h2b, Mm);

    // ---- Gram matrices (bf16 out): z<32 -> B=h1b, z>=32 -> B=h2b ----
    mg(stream, h1b, h1b, nullptr, nullptr, nullptr, G11, S, S, S, Mm,
       Mm, Mm, S, 0, nSM, 32 * nSM, nSM, 32, nSS, 64, 0);   // G11 | G12
    mg(stream, h2b, h1b, nullptr, nullptr, nullptr, G21, S, S, S, Mm,
       Mm, Mm, S, 0, nSM, 32 * nSM, nSM, 32, nSS, 64, 0);   // G21 | G22

    // ---- loss ----
    loss_kernel<<<dim3(S, B), 256, 0, stream>>>(G11, G12, G21, G22, s_mask, a_mask, lossb);
    final_reduce<<<1, 256, 0, stream>>>(lossb, (float*)d_out, MT);
}

// Round 7
// 821.142 us; speedup vs baseline: 1.1405x; 1.1405x over previous
//
#include <hip/hip_runtime.h>
#include <math.h>

// DASCO forward, round 7: revert to materialized bf16 scores (R6's fused attn
// regressed: 2x score-MFMA + 2x exp work, 512-block grid). Consolidations:
// merged sem|dep adjacency GEMM (z=64, per-half bias), elementwise gcn-combine,
// z=2 batched projection head, single fused weight-cast kernel.
// B=32, S=512, D=768, M=384.

typedef __bf16 bf16x8 __attribute__((ext_vector_type(8)));
typedef __bf16 bf16x4 __attribute__((ext_vector_type(4)));
typedef float f32x4 __attribute__((ext_vector_type(4)));

__device__ __forceinline__ void glds16(const void* g, void* l) {
    __builtin_amdgcn_global_load_lds(
        (const __attribute__((address_space(1))) unsigned*)g,
        (__attribute__((address_space(3))) unsigned*)l, 16, 0, 0);
}

__device__ __forceinline__ float sigf(float x) { return 1.f / (1.f + __expf(-x)); }

// ---------------- bf16 MFMA GEMM, 128x128 tile, dbuf, m-innermost grid --------
// C[z][m][n] = sum_k A[z][m][k]*B[z][n][k] (+bias[(z/bzDiv)*bzStride + n]),
// act: 0 none; 1 relu; 2 elu; 4 relu+gate(E=Hold). Writes masked to n < nMax.
__global__ __launch_bounds__(256) void mfma_gemm(
    const __bf16* __restrict__ A, const __bf16* __restrict__ B,
    const float* __restrict__ bias, int bzDiv, int bzStride,
    const float* __restrict__ E,
    float* __restrict__ Cf, __bf16* __restrict__ Cb,
    int K, int lda, int ldb, int ldc, int nMax,
    long sAo, long sAi, long sBo, long sBi, int zInner, long sC, int act)
{
    __shared__ __bf16 As[2][128 * 32];
    __shared__ __bf16 Bs[2][128 * 32];
    int z = blockIdx.z;
    long aBase = (long)(z / zInner) * sAo + (long)(z % zInner) * sAi;
    long bBase = (long)(z / zInner) * sBo + (long)(z % zInner) * sBi;
    long cBase = (long)z * sC;
    int m0 = blockIdx.x * 128, n0 = blockIdx.y * 128;
    int tid = threadIdx.x;
    int wave = tid >> 6, lane = tid & 63;
    int wm = wave >> 1, wn = wave & 1;

    int e0 = tid, e1 = tid + 256;
    const __bf16* Ag0 = A + aBase + (long)(m0 + (e0 >> 2)) * lda + (e0 & 3) * 8;
    const __bf16* Ag1 = A + aBase + (long)(m0 + (e1 >> 2)) * lda + (e1 & 3) * 8;
    const __bf16* Bg0 = B + bBase + (long)(n0 + (e0 >> 2)) * ldb + (e0 & 3) * 8;
    const __bf16* Bg1 = B + bBase + (long)(n0 + (e1 >> 2)) * ldb + (e1 & 3) * 8;

    f32x4 acc[4][4];
#pragma unroll
    for (int i = 0; i < 4; i++)
#pragma unroll
        for (int j = 0; j < 4; j++) acc[i][j] = (f32x4){0.f, 0.f, 0.f, 0.f};

    int arow = wm * 64 + (lane & 15);
    int brow = wn * 64 + (lane & 15);
    int quad = lane >> 4;

    glds16(Ag0, As[0] + e0 * 8); glds16(Ag1, As[0] + e1 * 8);
    glds16(Bg0, Bs[0] + e0 * 8); glds16(Bg1, Bs[0] + e1 * 8);

    int cur = 0;
    for (int k0 = 0; k0 < K; k0 += 32) {
        __syncthreads();
        if (k0 + 32 < K) {
            int nk = k0 + 32, nb = cur ^ 1;
            glds16(Ag0 + nk, As[nb] + e0 * 8); glds16(Ag1 + nk, As[nb] + e1 * 8);
            glds16(Bg0 + nk, Bs[nb] + e0 * 8); glds16(Bg1 + nk, Bs[nb] + e1 * 8);
        }
        const bf16x8* Asv = (const bf16x8*)As[cur];
        const bf16x8* Bsv = (const bf16x8*)Bs[cur];
        bf16x8 af[4], bfr[4];
#pragma unroll
        for (int mi = 0; mi < 4; mi++) af[mi] = Asv[(arow + mi * 16) * 4 + quad];
#pragma unroll
        for (int ni = 0; ni < 4; ni++) bfr[ni] = Bsv[(brow + ni * 16) * 4 + quad];
#pragma unroll
        for (int mi = 0; mi < 4; mi++)
#pragma unroll
            for (int ni = 0; ni < 4; ni++)
                acc[mi][ni] = __builtin_amdgcn_mfma_f32_16x16x32_bf16(
                    af[mi], bfr[ni], acc[mi][ni], 0, 0, 0);
        cur ^= 1;
    }

    int crow = m0 + wm * 64 + (lane >> 4) * 4;
    int ccol = n0 + wn * 64 + (lane & 15);
    const float* biasz = bias ? bias + (z / bzDiv) * bzStride : nullptr;
    float bv[4];
#pragma unroll
    for (int ni = 0; ni < 4; ni++) {
        int col = ccol + ni * 16;
        bv[ni] = (biasz && col < nMax) ? biasz[col] : 0.f;
    }
#pragma unroll
    for (int mi = 0; mi < 4; mi++) {
#pragma unroll
        for (int ni = 0; ni < 4; ni++) {
            int col = ccol + ni * 16;
            if (col >= nMax) continue;
#pragma unroll
            for (int r = 0; r < 4; r++) {
                float v = acc[mi][ni][r] + bv[ni];
                long idx = cBase + (long)(crow + mi * 16 + r) * ldc + col;
                if (act == 1) v = fmaxf(v, 0.f);
                else if (act == 2) v = (v > 0.f) ? v : expm1f(v);
                else if (act == 4) { float e = E[idx]; v = fmaxf(v, 0.f); float g = sigf(e); v = g * v + (1.f - g) * e; }
                if (Cf) Cf[idx] = v;
                if (Cb) Cb[idx] = (__bf16)v;
            }
        }
    }
}

// ---------------- fused weight transpose-casts (10 weights, one dispatch) -----
struct WCast {
    const float* src[10];
    unsigned dstOff[10];   // element offset into bf16 weight region
    int R[10], C[10];
    int start[11];         // cumulative 32x32 tile starts, start[10] = total
};

__global__ __launch_bounds__(256) void castW_kernel(WCast wc, __bf16* wb)
{
    __shared__ float t[32][33];
    int bid = blockIdx.x;
    int e = 0;
    while (bid >= wc.start[e + 1]) e++;
    int tt = bid - wc.start[e];
    int cT = wc.C[e] >> 5;
    int ty = tt / cT, tx = tt - ty * cT;
    const float* in = wc.src[e];
    __bf16* out = wb + wc.dstOff[e];
    int R = wc.R[e], C = wc.C[e];
    int r0 = ty * 32, c0 = tx * 32;
    int tid = threadIdx.x;
    int r = tid >> 3, c4 = (tid & 7) * 4;
    float4 v = *(const float4*)(in + (long)(r0 + r) * C + c0 + c4);
    t[r][c4] = v.x; t[r][c4 + 1] = v.y; t[r][c4 + 2] = v.z; t[r][c4 + 3] = v.w;
    __syncthreads();
    int c = tid >> 3, r4 = (tid & 7) * 4;
    bf16x4 o;
    o[0] = (__bf16)t[r4 + 0][c]; o[1] = (__bf16)t[r4 + 1][c];
    o[2] = (__bf16)t[r4 + 2][c]; o[3] = (__bf16)t[r4 + 3][c];
    *(bf16x4*)(out + (long)(c0 + c) * R + r0 + r4) = o;
}

// ---------------- plain casts ----------------
__global__ void cast_bf16_kernel(const float* __restrict__ in, __bf16* __restrict__ out, long n4)
{
    long i = (long)blockIdx.x * blockDim.x + threadIdx.x;
    if (i < n4) {
        float4 v = ((const float4*)in)[i];
        bf16x4 o; o[0] = (__bf16)v.x; o[1] = (__bf16)v.y; o[2] = (__bf16)v.z; o[3] = (__bf16)v.w;
        ((bf16x4*)out)[i] = o;
    }
}

// ---------------- attention softmax + head-mean -> adj_ag (bf16 in/out) -------
__global__ __launch_bounds__(256) void softmax_combine(
    const __bf16* __restrict__ scores, const int* __restrict__ attn_mask,
    __bf16* __restrict__ adj_agb, int b0)
{
    const int S = 512;
    int s = blockIdx.x, bl = blockIdx.y, b = b0 + bl;
    int tid = threadIdx.x;
    const float scale = 0.1020620726159658f;  // 1/sqrt(96)
    int t0 = tid, t1 = tid + 256;
    int cm0 = attn_mask[b * S + t0], cm1 = attn_mask[b * S + t1];
    float vals[8][2], part[8];
#pragma unroll
    for (int h = 0; h < 8; ++h) {
        long rb = ((long)(bl * 8 + h) * S + s) * S;
        float r0 = (float)scores[rb + t0], r1 = (float)scores[rb + t1];
        vals[h][0] = cm0 ? __expf(r0 * scale) : 0.f;
        vals[h][1] = cm1 ? __expf(r1 * scale) : 0.f;
        part[h] = vals[h][0] + vals[h][1];
    }
    __shared__ float red[4][8];
    __shared__ float linv[8];
    int lane = tid & 63, w = tid >> 6;
#pragma unroll
    for (int h = 0; h < 8; ++h) {
        float v = part[h];
        for (int o = 32; o > 0; o >>= 1) v += __shfl_down(v, o);
        if (lane == 0) red[w][h] = v;
    }
    __syncthreads();
    if (tid < 8) {
        float l = red[0][tid] + red[1][tid] + red[2][tid] + red[3][tid];
        linv[tid] = 1.f / fmaxf(l, 1e-30f);
    }
    __syncthreads();
    float rowmask = attn_mask[b * S + s] ? 1.f : 0.f;
    float a0 = 0.f, a1 = 0.f;
#pragma unroll
    for (int h = 0; h < 8; ++h) { a0 += vals[h][0] * linv[h]; a1 += vals[h][1] * linv[h]; }
    a0 *= 0.125f; a1 *= 0.125f;
    if (t0 == s) a0 = 1.f;
    if (t1 == s) a1 = 1.f;
    long ob = ((long)b * S + s) * S;
    adj_agb[ob + t0] = (__bf16)(rowmask * a0);
    adj_agb[ob + t1] = (__bf16)(rowmask * a1);
}

// ---------------- gcn combine: Icom = (1-0.6 sig(d)) s + 0.6 sig(d) d ---------
// IsemIdep: [2][16384][384] fp32 (s then d). Optional bf16 copy of s.
__global__ void gcn_combine2(const float* __restrict__ IsemIdep,
                             __bf16* __restrict__ Icomb, __bf16* __restrict__ Isemb,
                             long n4)
{
    long i = (long)blockIdx.x * blockDim.x + threadIdx.x;
    if (i >= n4) return;
    float4 s = ((const float4*)IsemIdep)[i];
    float4 d = ((const float4*)(IsemIdep + n4 * 4))[i];
    bf16x4 o, ob;
    float g;
    g = 0.6f * sigf(d.x); o[0] = (__bf16)((1.f - g) * s.x + g * d.x);
    g = 0.6f * sigf(d.y); o[1] = (__bf16)((1.f - g) * s.y + g * d.y);
    g = 0.6f * sigf(d.z); o[2] = (__bf16)((1.f - g) * s.z + g * d.z);
    g = 0.6f * sigf(d.w); o[3] = (__bf16)((1.f - g) * s.w + g * d.w);
    ((bf16x4*)Icomb)[i] = o;
    if (Isemb) {
        ob[0] = (__bf16)s.x; ob[1] = (__bf16)s.y; ob[2] = (__bf16)s.z; ob[3] = (__bf16)s.w;
        ((bf16x4*)Isemb)[i] = ob;
    }
}

// ---------------- row L2-normalize + bf16 copy ----------------
__global__ __launch_bounds__(128) void rownorm(
    const float* __restrict__ h1, const float* __restrict__ h2,
    __bf16* __restrict__ h1b, __bf16* __restrict__ h2b, int Dm)
{
    const float* p = (blockIdx.y ? h2 : h1) + (long)blockIdx.x * Dm;
    __bf16* pb = (blockIdx.y ? h2b : h1b) + (long)blockIdx.x * Dm;
    int tid = threadIdx.x;
    float ss = 0.f;
    for (int i = tid; i < Dm; i += 128) { float v = p[i]; ss += v * v; }
    for (int o = 32; o > 0; o >>= 1) ss += __shfl_down(ss, o);
    __shared__ float sb[2];
    __shared__ float scale;
    if ((tid & 63) == 0) sb[tid >> 6] = ss;
    __syncthreads();
    if (tid == 0) scale = 1.f / fmaxf(sqrtf(sb[0] + sb[1]), 1e-12f);
    __syncthreads();
    for (int i = tid; i < Dm; i += 128) pb[i] = (__bf16)(p[i] * scale);
}

// ---------------- fused symmetric scope loss per (b,s) row (bf16 G) -----------
__global__ __launch_bounds__(256) void loss_kernel(
    const __bf16* __restrict__ G11, const __bf16* __restrict__ G12,
    const __bf16* __restrict__ G21, const __bf16* __restrict__ G22,
    const int* __restrict__ s_mask, const int* __restrict__ a_mask,
    float* __restrict__ lossb)
{
    const int S = 512;
    int s = blockIdx.x, b = blockIdx.y;
    int tid = threadIdx.x;
    if (a_mask[b * S + s] == 0) {
        if (tid == 0) lossb[b * S + s] = 0.f;
        return;
    }
    long base = ((long)b * S + s) * S;
    const float it = 1.f / 0.07f;
    float sms = s_mask[b * S + s] ? 1.f : 0.f;
    float d12 = (float)G12[base + s], d21 = (float)G21[base + s];
    float w1i = sms * d12 * it, w2i = sms * d21 * it;
    float p[8];
#pragma unroll
    for (int h = 0; h < 8; h++) p[h] = 0.f;
#pragma unroll
    for (int j = 0; j < 2; j++) {
        int t = tid + j * 256;
        bool smt = s_mask[b * S + t] != 0;
        bool off = (t != s);
        float g11 = (float)G11[base + t], g12 = (float)G12[base + t];
        float g21 = (float)G21[base + t], g22 = (float)G22[base + t];
        float e11 = __expf(g11 * it), e12 = __expf(g12 * it);
        float e21 = __expf(g21 * it), e22 = __expf(g22 * it);
        p[2] += e11; p[3] += e12; p[6] += e22; p[7] += e21;
        if (off) {
            p[0] += smt ? e11 : 1.f;
            p[4] += smt ? e22 : 1.f;
            p[1] += smt ? __expf(g12 * w1i) : 1.f;
            p[5] += smt ? __expf(g21 * w2i) : 1.f;
        }
    }
    __shared__ float red[4][8];
    int lane = tid & 63, w = tid >> 6;
#pragma unroll
    for (int h = 0; h < 8; h++) {
        float v = p[h];
        for (int o = 32; o > 0; o >>= 1) v += __shfl_down(v, o);
        if (lane == 0) red[w][h] = v;
    }
    __syncthreads();
    if (tid == 0) {
        float r[8];
#pragma unroll
        for (int h = 0; h < 8; h++) r[h] = red[0][h] + red[1][h] + red[2][h] + red[3][h];
        float g11ss = (float)G11[base + s], g22ss = (float)G22[base + s];
        float pos1 = __expf(w1i) + r[0] + r[1];
        float alle1 = r[2] - __expf(g11ss * it) + r[3];
        float pos2 = __expf(w2i) + r[4] + r[5];
        float alle2 = r[6] - __expf(g22ss * it) + r[7];
        lossb[b * S + s] = 0.5f * ((__logf(alle1) - __logf(pos1)) +
                                   (__logf(alle2) - __logf(pos2)));
    }
}

__global__ __launch_bounds__(256) void final_reduce(
    const float* __restrict__ lossb, float* __restrict__ out, int n)
{
    int tid = threadIdx.x;
    float s = 0.f;
    for (int i = tid; i < n; i += 256) s += lossb[i];
    for (int o = 32; o > 0; o >>= 1) s += __shfl_down(s, o);
    __shared__ float sb[4];
    if ((tid & 63) == 0) sb[tid >> 6] = s;
    __syncthreads();
    if (tid == 0) out[0] = (sb[0] + sb[1] + sb[2] + sb[3]) / (float)n;
}

// ---------------- host ----------------
static inline void mg(hipStream_t st, const __bf16* A, const __bf16* B,
                      const float* bias, int bzDiv, int bzStride,
                      const float* E, float* Cf, __bf16* Cb,
                      int M, int Npad, int nMax, int K, int lda, int ldb, int ldc,
                      long sAo, long sAi, long sBo, long sBi, int zInner, long sC, int nz,
                      int act)
{
    dim3 g(M / 128, Npad / 128, nz);
    mfma_gemm<<<g, 256, 0, st>>>(A, B, bias, bzDiv, bzStride, E, Cf, Cb,
                                 K, lda, ldb, ldc, nMax,
                                 sAo, sAi, sBo, sBi, zInner, sC, act);
}

extern "C" void kernel_launch(void* const* d_in, const int* in_sizes, int n_in,
                              void* d_out, int out_size, void* d_ws, size_t ws_size,
                              hipStream_t stream)
{
    const int B = 32, S = 512, D = 768, Mm = 384;
    const int MT = B * S;  // 16384
    const float* X    = (const float*)d_in[0];
    const float* adjm = (const float*)d_in[1];
    const int* attn_mask = (const int*)d_in[2];
    const int* s_mask    = (const int*)d_in[3];
    const int* a_mask    = (const int*)d_in[4];
    const float* Wq = (const float*)d_in[5],  *bq = (const float*)d_in[6];
    const float* Wk = (const float*)d_in[7],  *bk = (const float*)d_in[8];
    const float* semW0 = (const float*)d_in[9],  *semb0 = (const float*)d_in[10];
    const float* semW1 = (const float*)d_in[11], *semb1 = (const float*)d_in[12];
    const float* depW0 = (const float*)d_in[13], *depb0 = (const float*)d_in[14];
    const float* depW1 = (const float*)d_in[15], *depb1 = (const float*)d_in[16];
    const float* fc1W = (const float*)d_in[17], *fc1b = (const float*)d_in[18];
    const float* fc2W = (const float*)d_in[19], *fc2b = (const float*)d_in[20];
    const float* fc3W = (const float*)d_in[21], *fc3b = (const float*)d_in[22];
    const float* fc4W = (const float*)d_in[23], *fc4b = (const float*)d_in[24];

    char* ws = (char*)d_ws;
    const size_t MB = 1u << 20;
    const size_t KB = 1u << 10;

    // rotating regions
    __bf16* Xb      = (__bf16*)(ws + 0 * MB);     // 24MB
    __bf16* adj_agb = (__bf16*)(ws + 24 * MB);    // 16MB \ contiguous
    __bf16* adjmb   = (__bf16*)(ws + 40 * MB);    // 16MB /
    __bf16* qkb     = (__bf16*)(ws + 56 * MB);    // 48MB [16384][1536] (attn)
    __bf16* scoreB  = (__bf16*)(ws + 104 * MB);   // 64MB chunk (attn), ends 168
    __bf16* P64     = (__bf16*)(ws + 56 * MB);    // 24MB [64][384][512] (layers)
    float*  IsemId  = (float*)(ws + 80 * MB);     // 48MB [2][16384][384] fp32
    __bf16* Icomb   = (__bf16*)(ws + 128 * MB);   // 12MB
    float*  H       = (float*)(ws + 140 * MB);    // 24MB fp32
    __bf16* Hb      = (__bf16*)(ws + 164 * MB);   // 12MB \ contiguous pair
    __bf16* Isemb   = (__bf16*)(ws + 176 * MB);   // 12MB /   (ends 188)
    __bf16* t1b     = (__bf16*)(ws + 0 * MB);     // 2MB, 2 slices (proj; Xb dead)
    float*  h1      = (float*)(ws + 4 * MB);      // 24MB \ contiguous pair
    float*  h2      = (float*)(ws + 28 * MB);     // 24MB /   (adj dead)
    __bf16* h1b     = (__bf16*)(ws + 56 * MB);    // 12MB \ contiguous (P64 dead)
    __bf16* h2b     = (__bf16*)(ws + 68 * MB);    // 12MB /
    __bf16* G11     = (__bf16*)(ws + 80 * MB);    // 16MB x4 contiguous
    __bf16* G12     = (__bf16*)(ws + 96 * MB);
    __bf16* G21     = (__bf16*)(ws + 112 * MB);
    __bf16* G22     = (__bf16*)(ws + 128 * MB);   // ends 144

    // permanent weight region @192MB
    char* wreg = ws + 192 * MB;
    __bf16* wb     = (__bf16*)wreg;
    __bf16* WqkT   = (__bf16*)(wreg + 0 * KB);       // [1536][768]
    __bf16* semW0T = (__bf16*)(wreg + 2304 * KB);    // [384][768] \ contiguous
    __bf16* depW0T = (__bf16*)(wreg + 2880 * KB);    //            /
    __bf16* fc4WT  = (__bf16*)(wreg + 3456 * KB);
    __bf16* semW1T = (__bf16*)(wreg + 4032 * KB);    // [384][384] \ contiguous
    __bf16* depW1T = (__bf16*)(wreg + 4320 * KB);    //            /
    __bf16* fc3WT  = (__bf16*)(wreg + 4608 * KB);
    __bf16* fc1WT  = (__bf16*)(wreg + 4896 * KB);    // [128 pad][384]
    __bf16* fc2WT  = (__bf16*)(wreg + 4992 * KB);    // [384][32]
    float*  bqk    = (float*)(wreg + 5016 * KB);     // [1536]
    float*  sbd0   = (float*)(wreg + 5024 * KB);     // [768] semb0|depb0
    float*  sbd1   = (float*)(wreg + 5028 * KB);     // [768] semb1|depb1
    float*  lossb  = (float*)(wreg + 5036 * KB);     // 64KB

    long nSM = (long)S * Mm, nSS = (long)S * S;
    long nPM = (long)Mm * S;
    long hStride = 6291456;  // 12MB in bf16 elems / 24MB in floats

    // ---- casts ----
    cast_bf16_kernel<<<(MT * D / 4 + 255) / 256, 256, 0, stream>>>(X, Xb, (long)MT * D / 4);
    cast_bf16_kernel<<<((long)B * nSS / 4 + 255) / 256, 256, 0, stream>>>(adjm, adjmb, (long)B * nSS / 4);
    {
        WCast wc;
        const float* srcs[10] = {Wq, Wk, semW0, depW0, fc4W, semW1, depW1, fc3W, fc1W, fc2W};
        unsigned offs[10] = {0u, 589824u, 1179648u, 1474560u, 1769472u,
                             2064384u, 2211840u, 2359296u, 2506752u, 2555904u};
        int Rs[10] = {768, 768, 768, 768, 768, 384, 384, 384, 384, 32};
        int Cs[10] = {768, 768, 384, 384, 384, 384, 384, 384, 32, 384};
        int st = 0;
        for (int i = 0; i < 10; i++) {
            wc.src[i] = srcs[i]; wc.dstOff[i] = offs[i];
            wc.R[i] = Rs[i]; wc.C[i] = Cs[i];
            wc.start[i] = st; st += (Rs[i] / 32) * (Cs[i] / 32);
        }
        wc.start[10] = st;  // 2472
        castW_kernel<<<st, 256, 0, stream>>>(wc, wb);
    }
    hipMemsetAsync(fc1WT + 32 * Mm, 0, (size_t)96 * Mm * 2, stream);
    hipMemcpyAsync(bqk, bq, D * 4, hipMemcpyDeviceToDevice, stream);
    hipMemcpyAsync(bqk + D, bk, D * 4, hipMemcpyDeviceToDevice, stream);
    hipMemcpyAsync(sbd0, semb0, Mm * 4, hipMemcpyDeviceToDevice, stream);
    hipMemcpyAsync(sbd0 + Mm, depb0, Mm * 4, hipMemcpyDeviceToDevice, stream);
    hipMemcpyAsync(sbd1, semb1, Mm * 4, hipMemcpyDeviceToDevice, stream);
    hipMemcpyAsync(sbd1 + Mm, depb1, Mm * 4, hipMemcpyDeviceToDevice, stream);

    // ---- fused q|k projection ----
    mg(stream, Xb, WqkT, bqk, 1, 0, nullptr, nullptr, qkb, MT, 1536, 1536, D,
       D, D, 1536, 0, 0, 0, 0, 1, 0, 1, 0);

    // ---- attention: materialized bf16 scores, 2 chunks of 16 batches ----
    for (int c = 0; c < 2; c++) {
        const __bf16* qc = qkb + (long)c * 16 * S * 1536;
        mg(stream, qc, qc + 768, nullptr, 1, 0, nullptr, nullptr, scoreB, S, S, S, 96,
           1536, 1536, S, (long)S * 1536, 96, (long)S * 1536, 96, 8, nSS, 128, 0);
        softmax_combine<<<dim3(S, 16), 256, 0, stream>>>(scoreB, attn_mask, adj_agb, c * 16);
    }

    long n4 = (long)MT * Mm / 4;
    int cwg = (int)((n4 + 255) / 256);

    // ---- layer 0 ----
    // P64[z<32] = (X_b @ semW0)^T, P64[z>=32] = (X_b @ depW0)^T
    mg(stream, semW0T, Xb, nullptr, 1, 0, nullptr, nullptr, P64, Mm, S, S, D,
       D, D, S, (long)Mm * D, 0, 0, (long)S * D, 32, nPM, 64, 0);
    // merged adjacency: z<32 adj_ag@Psem+semb0 -> Isem; z>=32 adjm@Pdep+depb0 -> Idep
    mg(stream, adj_agb, P64, sbd0, 32, Mm, nullptr, IsemId, nullptr, S, Mm, Mm, S,
       S, S, Mm, 0, nSS, 0, nPM, 64, nSM, 64, 0);
    gcn_combine2<<<cwg, 256, 0, stream>>>(IsemId, Icomb, nullptr, n4);
    // H = X @ fc4W + fc4b
    mg(stream, Xb, fc4WT, fc4b, 1, 0, nullptr, H, nullptr, MT, Mm, Mm, D,
       D, D, Mm, 0, 0, 0, 0, 1, 0, 1, 0);
    // H = gate(H, relu(Icom @ fc3W + fc3b)), bf16 copy Hb
    mg(stream, Icomb, fc3WT, fc3b, 1, 0, H, H, Hb, MT, Mm, Mm, Mm,
       Mm, Mm, Mm, 0, 0, 0, 0, 1, 0, 1, 4);

    // ---- layer 1 ----
    mg(stream, semW1T, Hb, nullptr, 1, 0, nullptr, nullptr, P64, Mm, S, S, Mm,
       Mm, Mm, S, (long)Mm * Mm, 0, 0, nSM, 32, nPM, 64, 0);
    mg(stream, adj_agb, P64, sbd1, 32, Mm, nullptr, IsemId, nullptr, S, Mm, Mm, S,
       S, S, Mm, 0, nSS, 0, nPM, 64, nSM, 64, 0);
    gcn_combine2<<<cwg, 256, 0, stream>>>(IsemId, Icomb, Isemb, n4);
    mg(stream, Icomb, fc3WT, fc3b, 1, 0, H, nullptr, Hb, MT, Mm, Mm, Mm,
       Mm, Mm, Mm, 0, 0, 0, 0, 1, 0, 1, 4);

    // ---- projection heads, z=2 (z0: Hb->h1, z1: Isemb->h2) ----
    mg(stream, Hb, fc1WT, fc1b, 1, 0, nullptr, nullptr, t1b, MT, 128, 32, Mm,
       Mm, Mm, 32, 0, hStride, 0, 0, 2, (long)MT * 32, 2, 2);
    mg(stream, t1b, fc2WT, fc2b, 1, 0, nullptr, h1, nullptr, MT, Mm, Mm, 32,
       32, 32, Mm, 0, (long)MT * 32, 0, 0, 2, hStride, 2, 0);

    rownorm<<<dim3(MT, 2), 128, 0, stream>>>(h1, h2, h1b, h2b, Mm);

    // ---- Gram matrices (bf16): z<32 -> B=h1b, z>=32 -> B=h2b ----
    mg(stream, h1b, h1b, nullptr, 1, 0, nullptr, nullptr, G11, S, S, S, Mm,
       Mm, Mm, S, 0, nSM, 32 * nSM, nSM, 32, nSS, 64, 0);   // G11 | G12
    mg(stream, h2b, h1b, nullptr, 1, 0, nullptr, nullptr, G21, S, S, S, Mm,
       Mm, Mm, S, 0, nSM, 32 * nSM, nSM, 32, nSS, 64, 0);   // G21 | G22

    // ---- loss ----
    loss_kernel<<<dim3(S, B), 256, 0, stream>>>(G11, G12, G21, G22, s_mask, a_mask, lossb);
    final_reduce<<<1, 256, 0, stream>>>(lossb, (float*)d_out, MT);
}

// Round 8
// 817.789 us; speedup vs baseline: 1.1452x; 1.0041x over previous
//
#include <hip/hip_runtime.h>
#include <math.h>

// DASCO forward, round 8: R7 + register-staged GEMM pipeline. global_load tile
// k+1 -> VGPRs, ds_write it next iteration (vmcnt wait lands one full iter
// after issue), raw "s_waitcnt lgkmcnt(0); s_barrier" so in-flight global
// loads cross the barrier (no vmcnt(0) drain). B=32, S=512, D=768, M=384.

typedef __bf16 bf16x8 __attribute__((ext_vector_type(8)));
typedef __bf16 bf16x4 __attribute__((ext_vector_type(4)));
typedef float f32x4 __attribute__((ext_vector_type(4)));

#define LGKM_BARRIER() asm volatile("s_waitcnt lgkmcnt(0)\ns_barrier" ::: "memory")

__device__ __forceinline__ float sigf(float x) { return 1.f / (1.f + __expf(-x)); }

// ---------------- bf16 MFMA GEMM, 128x128 tile, reg-staged dbuf --------------
// C[z][m][n] = sum_k A[z][m][k]*B[z][n][k] (+bias[(z/bzDiv)*bzStride + n]),
// act: 0 none; 1 relu; 2 elu; 4 relu+gate(E=Hold). Writes masked to n < nMax.
// Grid: x = m-blocks (innermost -> XCD L2 locality), y = n-blocks, z = batch.
__global__ __launch_bounds__(256) void mfma_gemm(
    const __bf16* __restrict__ A, const __bf16* __restrict__ B,
    const float* __restrict__ bias, int bzDiv, int bzStride,
    const float* __restrict__ E,
    float* __restrict__ Cf, __bf16* __restrict__ Cb,
    int K, int lda, int ldb, int ldc, int nMax,
    long sAo, long sAi, long sBo, long sBi, int zInner, long sC, int act)
{
    __shared__ __bf16 As[2][128 * 32];
    __shared__ __bf16 Bs[2][128 * 32];
    int z = blockIdx.z;
    long aBase = (long)(z / zInner) * sAo + (long)(z % zInner) * sAi;
    long bBase = (long)(z / zInner) * sBo + (long)(z % zInner) * sBi;
    long cBase = (long)z * sC;
    int m0 = blockIdx.x * 128, n0 = blockIdx.y * 128;
    int tid = threadIdx.x;
    int wave = tid >> 6, lane = tid & 63;
    int wm = wave >> 1, wn = wave & 1;

    // staging: element e in [0,512): row=e>>2 (0..127), kpart=(e&3)*8
    int e0 = tid, e1 = tid + 256;
    const __bf16* Ag0 = A + aBase + (long)(m0 + (e0 >> 2)) * lda + (e0 & 3) * 8;
    const __bf16* Ag1 = A + aBase + (long)(m0 + (e1 >> 2)) * lda + (e1 & 3) * 8;
    const __bf16* Bg0 = B + bBase + (long)(n0 + (e0 >> 2)) * ldb + (e0 & 3) * 8;
    const __bf16* Bg1 = B + bBase + (long)(n0 + (e1 >> 2)) * ldb + (e1 & 3) * 8;

    f32x4 acc[4][4];
#pragma unroll
    for (int i = 0; i < 4; i++)
#pragma unroll
        for (int j = 0; j < 4; j++) acc[i][j] = (f32x4){0.f, 0.f, 0.f, 0.f};

    int arow = wm * 64 + (lane & 15);
    int brow = wn * 64 + (lane & 15);
    int quad = lane >> 4;

    // prologue: tile0 -> regs -> LDS[0]; tile1 -> regs (stays in flight)
    bf16x8 ra0 = *(const bf16x8*)Ag0, ra1 = *(const bf16x8*)Ag1;
    bf16x8 rb0 = *(const bf16x8*)Bg0, rb1 = *(const bf16x8*)Bg1;
    *(bf16x8*)(As[0] + e0 * 8) = ra0; *(bf16x8*)(As[0] + e1 * 8) = ra1;
    *(bf16x8*)(Bs[0] + e0 * 8) = rb0; *(bf16x8*)(Bs[0] + e1 * 8) = rb1;
    if (K > 32) {
        ra0 = *(const bf16x8*)(Ag0 + 32); ra1 = *(const bf16x8*)(Ag1 + 32);
        rb0 = *(const bf16x8*)(Bg0 + 32); rb1 = *(const bf16x8*)(Bg1 + 32);
    }
    LGKM_BARRIER();

    int cur = 0;
    for (int k0 = 0; k0 < K; k0 += 32) {
        if (k0 + 32 < K) {
            // publish tile k0+32 (regs -> LDS[cur^1]); vmcnt wait lands here,
            // one full iteration after the loads were issued.
            int nb = cur ^ 1;
            *(bf16x8*)(As[nb] + e0 * 8) = ra0; *(bf16x8*)(As[nb] + e1 * 8) = ra1;
            *(bf16x8*)(Bs[nb] + e0 * 8) = rb0; *(bf16x8*)(Bs[nb] + e1 * 8) = rb1;
            if (k0 + 64 < K) {
                int nk = k0 + 64;
                ra0 = *(const bf16x8*)(Ag0 + nk); ra1 = *(const bf16x8*)(Ag1 + nk);
                rb0 = *(const bf16x8*)(Bg0 + nk); rb1 = *(const bf16x8*)(Bg1 + nk);
            }
        }
        const bf16x8* Asv = (const bf16x8*)As[cur];
        const bf16x8* Bsv = (const bf16x8*)Bs[cur];
        bf16x8 af[4], bfr[4];
#pragma unroll
        for (int mi = 0; mi < 4; mi++) af[mi] = Asv[(arow + mi * 16) * 4 + quad];
#pragma unroll
        for (int ni = 0; ni < 4; ni++) bfr[ni] = Bsv[(brow + ni * 16) * 4 + quad];
#pragma unroll
        for (int mi = 0; mi < 4; mi++)
#pragma unroll
            for (int ni = 0; ni < 4; ni++)
                acc[mi][ni] = __builtin_amdgcn_mfma_f32_16x16x32_bf16(
                    af[mi], bfr[ni], acc[mi][ni], 0, 0, 0);
        LGKM_BARRIER();
        cur ^= 1;
    }

    int crow = m0 + wm * 64 + (lane >> 4) * 4;
    int ccol = n0 + wn * 64 + (lane & 15);
    const float* biasz = bias ? bias + (z / bzDiv) * bzStride : nullptr;
    float bv[4];
#pragma unroll
    for (int ni = 0; ni < 4; ni++) {
        int col = ccol + ni * 16;
        bv[ni] = (biasz && col < nMax) ? biasz[col] : 0.f;
    }
#pragma unroll
    for (int mi = 0; mi < 4; mi++) {
#pragma unroll
        for (int ni = 0; ni < 4; ni++) {
            int col = ccol + ni * 16;
            if (col >= nMax) continue;
#pragma unroll
            for (int r = 0; r < 4; r++) {
                float v = acc[mi][ni][r] + bv[ni];
                long idx = cBase + (long)(crow + mi * 16 + r) * ldc + col;
                if (act == 1) v = fmaxf(v, 0.f);
                else if (act == 2) v = (v > 0.f) ? v : expm1f(v);
                else if (act == 4) { float e = E[idx]; v = fmaxf(v, 0.f); float g = sigf(e); v = g * v + (1.f - g) * e; }
                if (Cf) Cf[idx] = v;
                if (Cb) Cb[idx] = (__bf16)v;
            }
        }
    }
}

// ---------------- fused weight transpose-casts (10 weights, one dispatch) -----
struct WCast {
    const float* src[10];
    unsigned dstOff[10];
    int R[10], C[10];
    int start[11];
};

__global__ __launch_bounds__(256) void castW_kernel(WCast wc, __bf16* wb)
{
    __shared__ float t[32][33];
    int bid = blockIdx.x;
    int e = 0;
    while (bid >= wc.start[e + 1]) e++;
    int tt = bid - wc.start[e];
    int cT = wc.C[e] >> 5;
    int ty = tt / cT, tx = tt - ty * cT;
    const float* in = wc.src[e];
    __bf16* out = wb + wc.dstOff[e];
    int R = wc.R[e], C = wc.C[e];
    int r0 = ty * 32, c0 = tx * 32;
    int tid = threadIdx.x;
    int r = tid >> 3, c4 = (tid & 7) * 4;
    float4 v = *(const float4*)(in + (long)(r0 + r) * C + c0 + c4);
    t[r][c4] = v.x; t[r][c4 + 1] = v.y; t[r][c4 + 2] = v.z; t[r][c4 + 3] = v.w;
    __syncthreads();
    int c = tid >> 3, r4 = (tid & 7) * 4;
    bf16x4 o;
    o[0] = (__bf16)t[r4 + 0][c]; o[1] = (__bf16)t[r4 + 1][c];
    o[2] = (__bf16)t[r4 + 2][c]; o[3] = (__bf16)t[r4 + 3][c];
    *(bf16x4*)(out + (long)(c0 + c) * R + r0 + r4) = o;
}

// ---------------- plain casts ----------------
__global__ void cast_bf16_kernel(const float* __restrict__ in, __bf16* __restrict__ out, long n4)
{
    long i = (long)blockIdx.x * blockDim.x + threadIdx.x;
    if (i < n4) {
        float4 v = ((const float4*)in)[i];
        bf16x4 o; o[0] = (__bf16)v.x; o[1] = (__bf16)v.y; o[2] = (__bf16)v.z; o[3] = (__bf16)v.w;
        ((bf16x4*)out)[i] = o;
    }
}

// ---------------- attention softmax + head-mean -> adj_ag (bf16 in/out) -------
__global__ __launch_bounds__(256) void softmax_combine(
    const __bf16* __restrict__ scores, const int* __restrict__ attn_mask,
    __bf16* __restrict__ adj_agb, int b0)
{
    const int S = 512;
    int s = blockIdx.x, bl = blockIdx.y, b = b0 + bl;
    int tid = threadIdx.x;
    const float scale = 0.1020620726159658f;  // 1/sqrt(96)
    int t0 = tid, t1 = tid + 256;
    int cm0 = attn_mask[b * S + t0], cm1 = attn_mask[b * S + t1];
    float vals[8][2], part[8];
#pragma unroll
    for (int h = 0; h < 8; ++h) {
        long rb = ((long)(bl * 8 + h) * S + s) * S;
        float r0 = (float)scores[rb + t0], r1 = (float)scores[rb + t1];
        vals[h][0] = cm0 ? __expf(r0 * scale) : 0.f;
        vals[h][1] = cm1 ? __expf(r1 * scale) : 0.f;
        part[h] = vals[h][0] + vals[h][1];
    }
    __shared__ float red[4][8];
    __shared__ float linv[8];
    int lane = tid & 63, w = tid >> 6;
#pragma unroll
    for (int h = 0; h < 8; ++h) {
        float v = part[h];
        for (int o = 32; o > 0; o >>= 1) v += __shfl_down(v, o);
        if (lane == 0) red[w][h] = v;
    }
    __syncthreads();
    if (tid < 8) {
        float l = red[0][tid] + red[1][tid] + red[2][tid] + red[3][tid];
        linv[tid] = 1.f / fmaxf(l, 1e-30f);
    }
    __syncthreads();
    float rowmask = attn_mask[b * S + s] ? 1.f : 0.f;
    float a0 = 0.f, a1 = 0.f;
#pragma unroll
    for (int h = 0; h < 8; ++h) { a0 += vals[h][0] * linv[h]; a1 += vals[h][1] * linv[h]; }
    a0 *= 0.125f; a1 *= 0.125f;
    if (t0 == s) a0 = 1.f;
    if (t1 == s) a1 = 1.f;
    long ob = ((long)b * S + s) * S;
    adj_agb[ob + t0] = (__bf16)(rowmask * a0);
    adj_agb[ob + t1] = (__bf16)(rowmask * a1);
}

// ---------------- gcn combine ----------------
__global__ void gcn_combine2(const float* __restrict__ IsemIdep,
                             __bf16* __restrict__ Icomb, __bf16* __restrict__ Isemb,
                             long n4)
{
    long i = (long)blockIdx.x * blockDim.x + threadIdx.x;
    if (i >= n4) return;
    float4 s = ((const float4*)IsemIdep)[i];
    float4 d = ((const float4*)(IsemIdep + n4 * 4))[i];
    bf16x4 o, ob;
    float g;
    g = 0.6f * sigf(d.x); o[0] = (__bf16)((1.f - g) * s.x + g * d.x);
    g = 0.6f * sigf(d.y); o[1] = (__bf16)((1.f - g) * s.y + g * d.y);
    g = 0.6f * sigf(d.z); o[2] = (__bf16)((1.f - g) * s.z + g * d.z);
    g = 0.6f * sigf(d.w); o[3] = (__bf16)((1.f - g) * s.w + g * d.w);
    ((bf16x4*)Icomb)[i] = o;
    if (Isemb) {
        ob[0] = (__bf16)s.x; ob[1] = (__bf16)s.y; ob[2] = (__bf16)s.z; ob[3] = (__bf16)s.w;
        ((bf16x4*)Isemb)[i] = ob;
    }
}

// ---------------- row L2-normalize + bf16 copy ----------------
__global__ __launch_bounds__(128) void rownorm(
    const float* __restrict__ h1, const float* __restrict__ h2,
    __bf16* __restrict__ h1b, __bf16* __restrict__ h2b, int Dm)
{
    const float* p = (blockIdx.y ? h2 : h1) + (long)blockIdx.x * Dm;
    __bf16* pb = (blockIdx.y ? h2b : h1b) + (long)blockIdx.x * Dm;
    int tid = threadIdx.x;
    float ss = 0.f;
    for (int i = tid; i < Dm; i += 128) { float v = p[i]; ss += v * v; }
    for (int o = 32; o > 0; o >>= 1) ss += __shfl_down(ss, o);
    __shared__ float sb[2];
    __shared__ float scale;
    if ((tid & 63) == 0) sb[tid >> 6] = ss;
    __syncthreads();
    if (tid == 0) scale = 1.f / fmaxf(sqrtf(sb[0] + sb[1]), 1e-12f);
    __syncthreads();
    for (int i = tid; i < Dm; i += 128) pb[i] = (__bf16)(p[i] * scale);
}

// ---------------- fused symmetric scope loss per (b,s) row (bf16 G) -----------
__global__ __launch_bounds__(256) void loss_kernel(
    const __bf16* __restrict__ G11, const __bf16* __restrict__ G12,
    const __bf16* __restrict__ G21, const __bf16* __restrict__ G22,
    const int* __restrict__ s_mask, const int* __restrict__ a_mask,
    float* __restrict__ lossb)
{
    const int S = 512;
    int s = blockIdx.x, b = blockIdx.y;
    int tid = threadIdx.x;
    if (a_mask[b * S + s] == 0) {
        if (tid == 0) lossb[b * S + s] = 0.f;
        return;
    }
    long base = ((long)b * S + s) * S;
    const float it = 1.f / 0.07f;
    float sms = s_mask[b * S + s] ? 1.f : 0.f;
    float d12 = (float)G12[base + s], d21 = (float)G21[base + s];
    float w1i = sms * d12 * it, w2i = sms * d21 * it;
    float p[8];
#pragma unroll
    for (int h = 0; h < 8; h++) p[h] = 0.f;
#pragma unroll
    for (int j = 0; j < 2; j++) {
        int t = tid + j * 256;
        bool smt = s_mask[b * S + t] != 0;
        bool off = (t != s);
        float g11 = (float)G11[base + t], g12 = (float)G12[base + t];
        float g21 = (float)G21[base + t], g22 = (float)G22[base + t];
        float e11 = __expf(g11 * it), e12 = __expf(g12 * it);
        float e21 = __expf(g21 * it), e22 = __expf(g22 * it);
        p[2] += e11; p[3] += e12; p[6] += e22; p[7] += e21;
        if (off) {
            p[0] += smt ? e11 : 1.f;
            p[4] += smt ? e22 : 1.f;
            p[1] += smt ? __expf(g12 * w1i) : 1.f;
            p[5] += smt ? __expf(g21 * w2i) : 1.f;
        }
    }
    __shared__ float red[4][8];
    int lane = tid & 63, w = tid >> 6;
#pragma unroll
    for (int h = 0; h < 8; h++) {
        float v = p[h];
        for (int o = 32; o > 0; o >>= 1) v += __shfl_down(v, o);
        if (lane == 0) red[w][h] = v;
    }
    __syncthreads();
    if (tid == 0) {
        float r[8];
#pragma unroll
        for (int h = 0; h < 8; h++) r[h] = red[0][h] + red[1][h] + red[2][h] + red[3][h];
        float g11ss = (float)G11[base + s], g22ss = (float)G22[base + s];
        float pos1 = __expf(w1i) + r[0] + r[1];
        float alle1 = r[2] - __expf(g11ss * it) + r[3];
        float pos2 = __expf(w2i) + r[4] + r[5];
        float alle2 = r[6] - __expf(g22ss * it) + r[7];
        lossb[b * S + s] = 0.5f * ((__logf(alle1) - __logf(pos1)) +
                                   (__logf(alle2) - __logf(pos2)));
    }
}

__global__ __launch_bounds__(256) void final_reduce(
    const float* __restrict__ lossb, float* __restrict__ out, int n)
{
    int tid = threadIdx.x;
    float s = 0.f;
    for (int i = tid; i < n; i += 256) s += lossb[i];
    for (int o = 32; o > 0; o >>= 1) s += __shfl_down(s, o);
    __shared__ float sb[4];
    if ((tid & 63) == 0) sb[tid >> 6] = s;
    __syncthreads();
    if (tid == 0) out[0] = (sb[0] + sb[1] + sb[2] + sb[3]) / (float)n;
}

// ---------------- host ----------------
static inline void mg(hipStream_t st, const __bf16* A, const __bf16* B,
                      const float* bias, int bzDiv, int bzStride,
                      const float* E, float* Cf, __bf16* Cb,
                      int M, int Npad, int nMax, int K, int lda, int ldb, int ldc,
                      long sAo, long sAi, long sBo, long sBi, int zInner, long sC, int nz,
                      int act)
{
    dim3 g(M / 128, Npad / 128, nz);
    mfma_gemm<<<g, 256, 0, st>>>(A, B, bias, bzDiv, bzStride, E, Cf, Cb,
                                 K, lda, ldb, ldc, nMax,
                                 sAo, sAi, sBo, sBi, zInner, sC, act);
}

extern "C" void kernel_launch(void* const* d_in, const int* in_sizes, int n_in,
                              void* d_out, int out_size, void* d_ws, size_t ws_size,
                              hipStream_t stream)
{
    const int B = 32, S = 512, D = 768, Mm = 384;
    const int MT = B * S;  // 16384
    const float* X    = (const float*)d_in[0];
    const float* adjm = (const float*)d_in[1];
    const int* attn_mask = (const int*)d_in[2];
    const int* s_mask    = (const int*)d_in[3];
    const int* a_mask    = (const int*)d_in[4];
    const float* Wq = (const float*)d_in[5],  *bq = (const float*)d_in[6];
    const float* Wk = (const float*)d_in[7],  *bk = (const float*)d_in[8];
    const float* semW0 = (const float*)d_in[9],  *semb0 = (const float*)d_in[10];
    const float* semW1 = (const float*)d_in[11], *semb1 = (const float*)d_in[12];
    const float* depW0 = (const float*)d_in[13], *depb0 = (const float*)d_in[14];
    const float* depW1 = (const float*)d_in[15], *depb1 = (const float*)d_in[16];
    const float* fc1W = (const float*)d_in[17], *fc1b = (const float*)d_in[18];
    const float* fc2W = (const float*)d_in[19], *fc2b = (const float*)d_in[20];
    const float* fc3W = (const float*)d_in[21], *fc3b = (const float*)d_in[22];
    const float* fc4W = (const float*)d_in[23], *fc4b = (const float*)d_in[24];

    char* ws = (char*)d_ws;
    const size_t MB = 1u << 20;
    const size_t KB = 1u << 10;

    // rotating regions
    __bf16* Xb      = (__bf16*)(ws + 0 * MB);     // 24MB
    __bf16* adj_agb = (__bf16*)(ws + 24 * MB);    // 16MB \ contiguous
    __bf16* adjmb   = (__bf16*)(ws + 40 * MB);    // 16MB /
    __bf16* qkb     = (__bf16*)(ws + 56 * MB);    // 48MB [16384][1536] (attn)
    __bf16* scoreB  = (__bf16*)(ws + 104 * MB);   // 64MB chunk (attn), ends 168
    __bf16* P64     = (__bf16*)(ws + 56 * MB);    // 24MB [64][384][512] (layers)
    float*  IsemId  = (float*)(ws + 80 * MB);     // 48MB [2][16384][384] fp32
    __bf16* Icomb   = (__bf16*)(ws + 128 * MB);   // 12MB
    float*  H       = (float*)(ws + 140 * MB);    // 24MB fp32
    __bf16* Hb      = (__bf16*)(ws + 164 * MB);   // 12MB \ contiguous pair
    __bf16* Isemb   = (__bf16*)(ws + 176 * MB);   // 12MB /   (ends 188)
    __bf16* t1b     = (__bf16*)(ws + 0 * MB);     // 2MB, 2 slices (proj; Xb dead)
    float*  h1      = (float*)(ws + 4 * MB);      // 24MB \ contiguous pair
    float*  h2      = (float*)(ws + 28 * MB);     // 24MB /   (adj dead)
    __bf16* h1b     = (__bf16*)(ws + 56 * MB);    // 12MB \ contiguous (P64 dead)
    __bf16* h2b     = (__bf16*)(ws + 68 * MB);    // 12MB /
    __bf16* G11     = (__bf16*)(ws + 80 * MB);    // 16MB x4 contiguous
    __bf16* G12     = (__bf16*)(ws + 96 * MB);
    __bf16* G21     = (__bf16*)(ws + 112 * MB);
    __bf16* G22     = (__bf16*)(ws + 128 * MB);   // ends 144

    // permanent weight region @192MB
    char* wreg = ws + 192 * MB;
    __bf16* wb     = (__bf16*)wreg;
    __bf16* WqkT   = (__bf16*)(wreg + 0 * KB);       // [1536][768]
    __bf16* semW0T = (__bf16*)(wreg + 2304 * KB);    // [384][768] \ contiguous
    __bf16* depW0T = (__bf16*)(wreg + 2880 * KB);    //            /
    __bf16* fc4WT  = (__bf16*)(wreg + 3456 * KB);
    __bf16* semW1T = (__bf16*)(wreg + 4032 * KB);    // [384][384] \ contiguous
    __bf16* depW1T = (__bf16*)(wreg + 4320 * KB);    //            /
    __bf16* fc3WT  = (__bf16*)(wreg + 4608 * KB);
    __bf16* fc1WT  = (__bf16*)(wreg + 4896 * KB);    // [128 pad][384]
    __bf16* fc2WT  = (__bf16*)(wreg + 4992 * KB);    // [384][32]
    float*  bqk    = (float*)(wreg + 5016 * KB);     // [1536]
    float*  sbd0   = (float*)(wreg + 5024 * KB);     // [768] semb0|depb0
    float*  sbd1   = (float*)(wreg + 5028 * KB);     // [768] semb1|depb1
    float*  lossb  = (float*)(wreg + 5036 * KB);     // 64KB

    long nSM = (long)S * Mm, nSS = (long)S * S;
    long nPM = (long)Mm * S;
    long hStride = 6291456;  // 12MB in bf16 elems / 24MB in floats

    // ---- casts ----
    cast_bf16_kernel<<<(MT * D / 4 + 255) / 256, 256, 0, stream>>>(X, Xb, (long)MT * D / 4);
    cast_bf16_kernel<<<((long)B * nSS / 4 + 255) / 256, 256, 0, stream>>>(adjm, adjmb, (long)B * nSS / 4);
    {
        WCast wc;
        const float* srcs[10] = {Wq, Wk, semW0, depW0, fc4W, semW1, depW1, fc3W, fc1W, fc2W};
        unsigned offs[10] = {0u, 589824u, 1179648u, 1474560u, 1769472u,
                             2064384u, 2211840u, 2359296u, 2506752u, 2555904u};
        int Rs[10] = {768, 768, 768, 768, 768, 384, 384, 384, 384, 32};
        int Cs[10] = {768, 768, 384, 384, 384, 384, 384, 384, 32, 384};
        int st = 0;
        for (int i = 0; i < 10; i++) {
            wc.src[i] = srcs[i]; wc.dstOff[i] = offs[i];
            wc.R[i] = Rs[i]; wc.C[i] = Cs[i];
            wc.start[i] = st; st += (Rs[i] / 32) * (Cs[i] / 32);
        }
        wc.start[10] = st;  // 2472
        castW_kernel<<<st, 256, 0, stream>>>(wc, wb);
    }
    hipMemsetAsync(fc1WT + 32 * Mm, 0, (size_t)96 * Mm * 2, stream);
    hipMemcpyAsync(bqk, bq, D * 4, hipMemcpyDeviceToDevice, stream);
    hipMemcpyAsync(bqk + D, bk, D * 4, hipMemcpyDeviceToDevice, stream);
    hipMemcpyAsync(sbd0, semb0, Mm * 4, hipMemcpyDeviceToDevice, stream);
    hipMemcpyAsync(sbd0 + Mm, depb0, Mm * 4, hipMemcpyDeviceToDevice, stream);
    hipMemcpyAsync(sbd1, semb1, Mm * 4, hipMemcpyDeviceToDevice, stream);
    hipMemcpyAsync(sbd1 + Mm, depb1, Mm * 4, hipMemcpyDeviceToDevice, stream);

    // ---- fused q|k projection ----
    mg(stream, Xb, WqkT, bqk, 1, 0, nullptr, nullptr, qkb, MT, 1536, 1536, D,
       D, D, 1536, 0, 0, 0, 0, 1, 0, 1, 0);

    // ---- attention: materialized bf16 scores, 2 chunks of 16 batches ----
    for (int c = 0; c < 2; c++) {
        const __bf16* qc = qkb + (long)c * 16 * S * 1536;
        mg(stream, qc, qc + 768, nullptr, 1, 0, nullptr, nullptr, scoreB, S, S, S, 96,
           1536, 1536, S, (long)S * 1536, 96, (long)S * 1536, 96, 8, nSS, 128, 0);
        softmax_combine<<<dim3(S, 16), 256, 0, stream>>>(scoreB, attn_mask, adj_agb, c * 16);
    }

    long n4 = (long)MT * Mm / 4;
    int cwg = (int)((n4 + 255) / 256);

    // ---- layer 0 ----
    mg(stream, semW0T, Xb, nullptr, 1, 0, nullptr, nullptr, P64, Mm, S, S, D,
       D, D, S, (long)Mm * D, 0, 0, (long)S * D, 32, nPM, 64, 0);
    mg(stream, adj_agb, P64, sbd0, 32, Mm, nullptr, IsemId, nullptr, S, Mm, Mm, S,
       S, S, Mm, 0, nSS, 0, nPM, 64, nSM, 64, 0);
    gcn_combine2<<<cwg, 256, 0, stream>>>(IsemId, Icomb, nullptr, n4);
    mg(stream, Xb, fc4WT, fc4b, 1, 0, nullptr, H, nullptr, MT, Mm, Mm, D,
       D, D, Mm, 0, 0, 0, 0, 1, 0, 1, 0);
    mg(stream, Icomb, fc3WT, fc3b, 1, 0, H, H, Hb, MT, Mm, Mm, Mm,
       Mm, Mm, Mm, 0, 0, 0, 0, 1, 0, 1, 4);

    // ---- layer 1 ----
    mg(stream, semW1T, Hb, nullptr, 1, 0, nullptr, nullptr, P64, Mm, S, S, Mm,
       Mm, Mm, S, (long)Mm * Mm, 0, 0, nSM, 32, nPM, 64, 0);
    mg(stream, adj_agb, P64, sbd1, 32, Mm, nullptr, IsemId, nullptr, S, Mm, Mm, S,
       S, S, Mm, 0, nSS, 0, nPM, 64, nSM, 64, 0);
    gcn_combine2<<<cwg, 256, 0, stream>>>(IsemId, Icomb, Isemb, n4);
    mg(stream, Icomb, fc3WT, fc3b, 1, 0, H, nullptr, Hb, MT, Mm, Mm, Mm,
       Mm, Mm, Mm, 0, 0, 0, 0, 1, 0, 1, 4);

    // ---- projection heads, z=2 (z0: Hb->h1, z1: Isemb->h2) ----
    mg(stream, Hb, fc1WT, fc1b, 1, 0, nullptr, nullptr, t1b, MT, 128, 32, Mm,
       Mm, Mm, 32, 0, hStride, 0, 0, 2, (long)MT * 32, 2, 2);
    mg(stream, t1b, fc2WT, fc2b, 1, 0, nullptr, h1, nullptr, MT, Mm, Mm, 32,
       32, 32, Mm, 0, (long)MT * 32, 0, 0, 2, hStride, 2, 0);

    rownorm<<<dim3(MT, 2), 128, 0, stream>>>(h1, h2, h1b, h2b, Mm);

    // ---- Gram matrices (bf16): z<32 -> B=h1b, z>=32 -> B=h2b ----
    mg(stream, h1b, h1b, nullptr, 1, 0, nullptr, nullptr, G11, S, S, S, Mm,
       Mm, Mm, S, 0, nSM, 32 * nSM, nSM, 32, nSS, 64, 0);   // G11 | G12
    mg(stream, h2b, h1b, nullptr, 1, 0, nullptr, nullptr, G21, S, S, S, Mm,
       Mm, Mm, S, 0, nSM, 32 * nSM, nSM, 32, nSS, 64, 0);   // G21 | G22

    // ---- loss ----
    loss_kernel<<<dim3(S, B), 256, 0, stream>>>(G11, G12, G21, G22, s_mask, a_mask, lossb);
    final_reduce<<<1, 256, 0, stream>>>(lossb, (float*)d_out, MT);
}

// Round 9
// 800.947 us; speedup vs baseline: 1.1693x; 1.0210x over previous
//
#include <hip/hip_runtime.h>
#include <math.h>

// DASCO forward, round 9: GEMM core reverted to R7 (glds16 + __syncthreads
// dbuf — R8's reg-staged pipeline regressed 74->121us on the q|k dispatch).
// Traffic cuts: all fp32 intermediates (IsemId, H, h1/h2) now bf16; adj-GEMM
// sem-half doubles as proj input; rownorm in place. B=32, S=512, D=768, M=384.

typedef __bf16 bf16x8 __attribute__((ext_vector_type(8)));
typedef __bf16 bf16x4 __attribute__((ext_vector_type(4)));
typedef float f32x4 __attribute__((ext_vector_type(4)));

__device__ __forceinline__ void glds16(const void* g, void* l) {
    __builtin_amdgcn_global_load_lds(
        (const __attribute__((address_space(1))) unsigned*)g,
        (__attribute__((address_space(3))) unsigned*)l, 16, 0, 0);
}

__device__ __forceinline__ float sigf(float x) { return 1.f / (1.f + __expf(-x)); }

// ---------------- bf16 MFMA GEMM, 128x128 tile, dbuf, m-innermost grid --------
// C[z][m][n] = sum_k A[z][m][k]*B[z][n][k] (+bias[(z/bzDiv)*bzStride + n]),
// act: 0 none; 1 relu; 2 elu; 4 relu+gate (E bf16, H_prev). n < nMax masked.
__global__ __launch_bounds__(256) void mfma_gemm(
    const __bf16* __restrict__ A, const __bf16* __restrict__ B,
    const float* __restrict__ bias, int bzDiv, int bzStride,
    const __bf16* __restrict__ E,
    float* __restrict__ Cf, __bf16* __restrict__ Cb,
    int K, int lda, int ldb, int ldc, int nMax,
    long sAo, long sAi, long sBo, long sBi, int zInner, long sC, int act)
{
    __shared__ __bf16 As[2][128 * 32];
    __shared__ __bf16 Bs[2][128 * 32];
    int z = blockIdx.z;
    long aBase = (long)(z / zInner) * sAo + (long)(z % zInner) * sAi;
    long bBase = (long)(z / zInner) * sBo + (long)(z % zInner) * sBi;
    long cBase = (long)z * sC;
    int m0 = blockIdx.x * 128, n0 = blockIdx.y * 128;
    int tid = threadIdx.x;
    int wave = tid >> 6, lane = tid & 63;
    int wm = wave >> 1, wn = wave & 1;

    int e0 = tid, e1 = tid + 256;
    const __bf16* Ag0 = A + aBase + (long)(m0 + (e0 >> 2)) * lda + (e0 & 3) * 8;
    const __bf16* Ag1 = A + aBase + (long)(m0 + (e1 >> 2)) * lda + (e1 & 3) * 8;
    const __bf16* Bg0 = B + bBase + (long)(n0 + (e0 >> 2)) * ldb + (e0 & 3) * 8;
    const __bf16* Bg1 = B + bBase + (long)(n0 + (e1 >> 2)) * ldb + (e1 & 3) * 8;

    f32x4 acc[4][4];
#pragma unroll
    for (int i = 0; i < 4; i++)
#pragma unroll
        for (int j = 0; j < 4; j++) acc[i][j] = (f32x4){0.f, 0.f, 0.f, 0.f};

    int arow = wm * 64 + (lane & 15);
    int brow = wn * 64 + (lane & 15);
    int quad = lane >> 4;

    glds16(Ag0, As[0] + e0 * 8); glds16(Ag1, As[0] + e1 * 8);
    glds16(Bg0, Bs[0] + e0 * 8); glds16(Bg1, Bs[0] + e1 * 8);

    int cur = 0;
    for (int k0 = 0; k0 < K; k0 += 32) {
        __syncthreads();
        if (k0 + 32 < K) {
            int nk = k0 + 32, nb = cur ^ 1;
            glds16(Ag0 + nk, As[nb] + e0 * 8); glds16(Ag1 + nk, As[nb] + e1 * 8);
            glds16(Bg0 + nk, Bs[nb] + e0 * 8); glds16(Bg1 + nk, Bs[nb] + e1 * 8);
        }
        const bf16x8* Asv = (const bf16x8*)As[cur];
        const bf16x8* Bsv = (const bf16x8*)Bs[cur];
        bf16x8 af[4], bfr[4];
#pragma unroll
        for (int mi = 0; mi < 4; mi++) af[mi] = Asv[(arow + mi * 16) * 4 + quad];
#pragma unroll
        for (int ni = 0; ni < 4; ni++) bfr[ni] = Bsv[(brow + ni * 16) * 4 + quad];
#pragma unroll
        for (int mi = 0; mi < 4; mi++)
#pragma unroll
            for (int ni = 0; ni < 4; ni++)
                acc[mi][ni] = __builtin_amdgcn_mfma_f32_16x16x32_bf16(
                    af[mi], bfr[ni], acc[mi][ni], 0, 0, 0);
        cur ^= 1;
    }

    int crow = m0 + wm * 64 + (lane >> 4) * 4;
    int ccol = n0 + wn * 64 + (lane & 15);
    const float* biasz = bias ? bias + (z / bzDiv) * bzStride : nullptr;
    float bv[4];
#pragma unroll
    for (int ni = 0; ni < 4; ni++) {
        int col = ccol + ni * 16;
        bv[ni] = (biasz && col < nMax) ? biasz[col] : 0.f;
    }
#pragma unroll
    for (int mi = 0; mi < 4; mi++) {
#pragma unroll
        for (int ni = 0; ni < 4; ni++) {
            int col = ccol + ni * 16;
            if (col >= nMax) continue;
#pragma unroll
            for (int r = 0; r < 4; r++) {
                float v = acc[mi][ni][r] + bv[ni];
                long idx = cBase + (long)(crow + mi * 16 + r) * ldc + col;
                if (act == 1) v = fmaxf(v, 0.f);
                else if (act == 2) v = (v > 0.f) ? v : expm1f(v);
                else if (act == 4) {
                    float e = (float)E[idx];
                    v = fmaxf(v, 0.f);
                    float g = sigf(e);
                    v = g * v + (1.f - g) * e;
                }
                if (Cf) Cf[idx] = v;
                if (Cb) Cb[idx] = (__bf16)v;
            }
        }
    }
}

// ---------------- fused weight transpose-casts (10 weights, one dispatch) -----
struct WCast {
    const float* src[10];
    unsigned dstOff[10];
    int R[10], C[10];
    int start[11];
};

__global__ __launch_bounds__(256) void castW_kernel(WCast wc, __bf16* wb)
{
    __shared__ float t[32][33];
    int bid = blockIdx.x;
    int e = 0;
    while (bid >= wc.start[e + 1]) e++;
    int tt = bid - wc.start[e];
    int cT = wc.C[e] >> 5;
    int ty = tt / cT, tx = tt - ty * cT;
    const float* in = wc.src[e];
    __bf16* out = wb + wc.dstOff[e];
    int R = wc.R[e], C = wc.C[e];
    int r0 = ty * 32, c0 = tx * 32;
    int tid = threadIdx.x;
    int r = tid >> 3, c4 = (tid & 7) * 4;
    float4 v = *(const float4*)(in + (long)(r0 + r) * C + c0 + c4);
    t[r][c4] = v.x; t[r][c4 + 1] = v.y; t[r][c4 + 2] = v.z; t[r][c4 + 3] = v.w;
    __syncthreads();
    int c = tid >> 3, r4 = (tid & 7) * 4;
    bf16x4 o;
    o[0] = (__bf16)t[r4 + 0][c]; o[1] = (__bf16)t[r4 + 1][c];
    o[2] = (__bf16)t[r4 + 2][c]; o[3] = (__bf16)t[r4 + 3][c];
    *(bf16x4*)(out + (long)(c0 + c) * R + r0 + r4) = o;
}

// ---------------- plain casts ----------------
__global__ void cast_bf16_kernel(const float* __restrict__ in, __bf16* __restrict__ out, long n4)
{
    long i = (long)blockIdx.x * blockDim.x + threadIdx.x;
    if (i < n4) {
        float4 v = ((const float4*)in)[i];
        bf16x4 o; o[0] = (__bf16)v.x; o[1] = (__bf16)v.y; o[2] = (__bf16)v.z; o[3] = (__bf16)v.w;
        ((bf16x4*)out)[i] = o;
    }
}

// ---------------- attention softmax + head-mean -> adj_ag (bf16 in/out) -------
__global__ __launch_bounds__(256) void softmax_combine(
    const __bf16* __restrict__ scores, const int* __restrict__ attn_mask,
    __bf16* __restrict__ adj_agb, int b0)
{
    const int S = 512;
    int s = blockIdx.x, bl = blockIdx.y, b = b0 + bl;
    int tid = threadIdx.x;
    const float scale = 0.1020620726159658f;  // 1/sqrt(96)
    int t0 = tid, t1 = tid + 256;
    int cm0 = attn_mask[b * S + t0], cm1 = attn_mask[b * S + t1];
    float vals[8][2], part[8];
#pragma unroll
    for (int h = 0; h < 8; ++h) {
        long rb = ((long)(bl * 8 + h) * S + s) * S;
        float r0 = (float)scores[rb + t0], r1 = (float)scores[rb + t1];
        vals[h][0] = cm0 ? __expf(r0 * scale) : 0.f;
        vals[h][1] = cm1 ? __expf(r1 * scale) : 0.f;
        part[h] = vals[h][0] + vals[h][1];
    }
    __shared__ float red[4][8];
    __shared__ float linv[8];
    int lane = tid & 63, w = tid >> 6;
#pragma unroll
    for (int h = 0; h < 8; ++h) {
        float v = part[h];
        for (int o = 32; o > 0; o >>= 1) v += __shfl_down(v, o);
        if (lane == 0) red[w][h] = v;
    }
    __syncthreads();
    if (tid < 8) {
        float l = red[0][tid] + red[1][tid] + red[2][tid] + red[3][tid];
        linv[tid] = 1.f / fmaxf(l, 1e-30f);
    }
    __syncthreads();
    float rowmask = attn_mask[b * S + s] ? 1.f : 0.f;
    float a0 = 0.f, a1 = 0.f;
#pragma unroll
    for (int h = 0; h < 8; ++h) { a0 += vals[h][0] * linv[h]; a1 += vals[h][1] * linv[h]; }
    a0 *= 0.125f; a1 *= 0.125f;
    if (t0 == s) a0 = 1.f;
    if (t1 == s) a1 = 1.f;
    long ob = ((long)b * S + s) * S;
    adj_agb[ob + t0] = (__bf16)(rowmask * a0);
    adj_agb[ob + t1] = (__bf16)(rowmask * a1);
}

// ---------------- gcn combine (bf16 in/out) ----------------
// IsIdb: [2][MT][384] bf16 (sem then dep). Icom = (1-0.6 sig(d)) s + 0.6 sig(d) d
__global__ void gcn_combine2(const __bf16* __restrict__ IsIdb,
                             __bf16* __restrict__ Icomb, long n8)
{
    long i = (long)blockIdx.x * blockDim.x + threadIdx.x;
    if (i >= n8) return;
    bf16x8 sv = ((const bf16x8*)IsIdb)[i];
    bf16x8 dv = ((const bf16x8*)(IsIdb + n8 * 8))[i];
    bf16x8 o;
#pragma unroll
    for (int j = 0; j < 8; j++) {
        float s = (float)sv[j], d = (float)dv[j];
        float g = 0.6f * sigf(d);
        o[j] = (__bf16)((1.f - g) * s + g * d);
    }
    ((bf16x8*)Icomb)[i] = o;
}

// ---------------- row L2-normalize, bf16 in place ----------------
__global__ __launch_bounds__(128) void rownorm(__bf16* __restrict__ hb, int Dm)
{
    __bf16* p = hb + (long)blockIdx.x * Dm;
    int tid = threadIdx.x;
    float ss = 0.f;
    for (int i = tid; i < Dm; i += 128) { float v = (float)p[i]; ss += v * v; }
    for (int o = 32; o > 0; o >>= 1) ss += __shfl_down(ss, o);
    __shared__ float sb[2];
    __shared__ float scale;
    if ((tid & 63) == 0) sb[tid >> 6] = ss;
    __syncthreads();
    if (tid == 0) scale = 1.f / fmaxf(sqrtf(sb[0] + sb[1]), 1e-12f);
    __syncthreads();
    for (int i = tid; i < Dm; i += 128) p[i] = (__bf16)((float)p[i] * scale);
}

// ---------------- fused symmetric scope loss per (b,s) row (bf16 G) -----------
__global__ __launch_bounds__(256) void loss_kernel(
    const __bf16* __restrict__ G11, const __bf16* __restrict__ G12,
    const __bf16* __restrict__ G21, const __bf16* __restrict__ G22,
    const int* __restrict__ s_mask, const int* __restrict__ a_mask,
    float* __restrict__ lossb)
{
    const int S = 512;
    int s = blockIdx.x, b = blockIdx.y;
    int tid = threadIdx.x;
    if (a_mask[b * S + s] == 0) {
        if (tid == 0) lossb[b * S + s] = 0.f;
        return;
    }
    long base = ((long)b * S + s) * S;
    const float it = 1.f / 0.07f;
    float sms = s_mask[b * S + s] ? 1.f : 0.f;
    float d12 = (float)G12[base + s], d21 = (float)G21[base + s];
    float w1i = sms * d12 * it, w2i = sms * d21 * it;
    float p[8];
#pragma unroll
    for (int h = 0; h < 8; h++) p[h] = 0.f;
#pragma unroll
    for (int j = 0; j < 2; j++) {
        int t = tid + j * 256;
        bool smt = s_mask[b * S + t] != 0;
        bool off = (t != s);
        float g11 = (float)G11[base + t], g12 = (float)G12[base + t];
        float g21 = (float)G21[base + t], g22 = (float)G22[base + t];
        float e11 = __expf(g11 * it), e12 = __expf(g12 * it);
        float e21 = __expf(g21 * it), e22 = __expf(g22 * it);
        p[2] += e11; p[3] += e12; p[6] += e22; p[7] += e21;
        if (off) {
            p[0] += smt ? e11 : 1.f;
            p[4] += smt ? e22 : 1.f;
            p[1] += smt ? __expf(g12 * w1i) : 1.f;
            p[5] += smt ? __expf(g21 * w2i) : 1.f;
        }
    }
    __shared__ float red[4][8];
    int lane = tid & 63, w = tid >> 6;
#pragma unroll
    for (int h = 0; h < 8; h++) {
        float v = p[h];
        for (int o = 32; o > 0; o >>= 1) v += __shfl_down(v, o);
        if (lane == 0) red[w][h] = v;
    }
    __syncthreads();
    if (tid == 0) {
        float r[8];
#pragma unroll
        for (int h = 0; h < 8; h++) r[h] = red[0][h] + red[1][h] + red[2][h] + red[3][h];
        float g11ss = (float)G11[base + s], g22ss = (float)G22[base + s];
        float pos1 = __expf(w1i) + r[0] + r[1];
        float alle1 = r[2] - __expf(g11ss * it) + r[3];
        float pos2 = __expf(w2i) + r[4] + r[5];
        float alle2 = r[6] - __expf(g22ss * it) + r[7];
        lossb[b * S + s] = 0.5f * ((__logf(alle1) - __logf(pos1)) +
                                   (__logf(alle2) - __logf(pos2)));
    }
}

__global__ __launch_bounds__(256) void final_reduce(
    const float* __restrict__ lossb, float* __restrict__ out, int n)
{
    int tid = threadIdx.x;
    float s = 0.f;
    for (int i = tid; i < n; i += 256) s += lossb[i];
    for (int o = 32; o > 0; o >>= 1) s += __shfl_down(s, o);
    __shared__ float sb[4];
    if ((tid & 63) == 0) sb[tid >> 6] = s;
    __syncthreads();
    if (tid == 0) out[0] = (sb[0] + sb[1] + sb[2] + sb[3]) / (float)n;
}

// ---------------- host ----------------
static inline void mg(hipStream_t st, const __bf16* A, const __bf16* B,
                      const float* bias, int bzDiv, int bzStride,
                      const __bf16* E, float* Cf, __bf16* Cb,
                      int M, int Npad, int nMax, int K, int lda, int ldb, int ldc,
                      long sAo, long sAi, long sBo, long sBi, int zInner, long sC, int nz,
                      int act)
{
    dim3 g(M / 128, Npad / 128, nz);
    mfma_gemm<<<g, 256, 0, st>>>(A, B, bias, bzDiv, bzStride, E, Cf, Cb,
                                 K, lda, ldb, ldc, nMax,
                                 sAo, sAi, sBo, sBi, zInner, sC, act);
}

extern "C" void kernel_launch(void* const* d_in, const int* in_sizes, int n_in,
                              void* d_out, int out_size, void* d_ws, size_t ws_size,
                              hipStream_t stream)
{
    const int B = 32, S = 512, D = 768, Mm = 384;
    const int MT = B * S;  // 16384
    const float* X    = (const float*)d_in[0];
    const float* adjm = (const float*)d_in[1];
    const int* attn_mask = (const int*)d_in[2];
    const int* s_mask    = (const int*)d_in[3];
    const int* a_mask    = (const int*)d_in[4];
    const float* Wq = (const float*)d_in[5],  *bq = (const float*)d_in[6];
    const float* Wk = (const float*)d_in[7],  *bk = (const float*)d_in[8];
    const float* semW0 = (const float*)d_in[9],  *semb0 = (const float*)d_in[10];
    const float* semW1 = (const float*)d_in[11], *semb1 = (const float*)d_in[12];
    const float* depW0 = (const float*)d_in[13], *depb0 = (const float*)d_in[14];
    const float* depW1 = (const float*)d_in[15], *depb1 = (const float*)d_in[16];
    const float* fc1W = (const float*)d_in[17], *fc1b = (const float*)d_in[18];
    const float* fc2W = (const float*)d_in[19], *fc2b = (const float*)d_in[20];
    const float* fc3W = (const float*)d_in[21], *fc3b = (const float*)d_in[22];
    const float* fc4W = (const float*)d_in[23], *fc4b = (const float*)d_in[24];

    char* ws = (char*)d_ws;
    const size_t MB = 1u << 20;
    const size_t KB = 1u << 10;

    // rotating regions
    __bf16* Xb      = (__bf16*)(ws + 0 * MB);     // 24MB
    __bf16* adj_agb = (__bf16*)(ws + 24 * MB);    // 16MB \ contiguous
    __bf16* adjmb   = (__bf16*)(ws + 40 * MB);    // 16MB /
    __bf16* qkb     = (__bf16*)(ws + 56 * MB);    // 48MB (attn)
    __bf16* scoreB  = (__bf16*)(ws + 104 * MB);   // 64MB chunk (attn), ends 168
    __bf16* P64     = (__bf16*)(ws + 56 * MB);    // 24MB [64][384][512] (layers)
    __bf16* IsIdb   = (__bf16*)(ws + 80 * MB);    // 24MB [2][MT][384] bf16
    __bf16* Isemb   = IsIdb;                      // sem half doubles as proj input
    __bf16* Icomb   = (__bf16*)(ws + 104 * MB);   // 12MB (scoreB dead)
    __bf16* Hpreb   = (__bf16*)(ws + 116 * MB);   // 12MB (fc4 out, pre-gate)
    __bf16* Hb      = (__bf16*)(ws + 128 * MB);   // 12MB (gated H)
    __bf16* t1b     = (__bf16*)(ws + 0 * MB);     // 2MB, 2 slices (Xb dead)
    __bf16* hb12    = (__bf16*)(ws + 140 * MB);   // 24MB [2][MT][384] h1|h2
    __bf16* h1b     = hb12;
    __bf16* h2b     = hb12 + (long)MT * Mm;
    __bf16* G11     = (__bf16*)(ws + 24 * MB);    // 16MB x4 contiguous (adj dead)
    __bf16* G12     = (__bf16*)(ws + 40 * MB);
    __bf16* G21     = (__bf16*)(ws + 56 * MB);
    __bf16* G22     = (__bf16*)(ws + 72 * MB);    // ends 88

    // permanent weight region @192MB
    char* wreg = ws + 192 * MB;
    __bf16* wb     = (__bf16*)wreg;
    __bf16* WqkT   = (__bf16*)(wreg + 0 * KB);       // [1536][768]
    __bf16* semW0T = (__bf16*)(wreg + 2304 * KB);    // [384][768] \ contiguous
    __bf16* depW0T = (__bf16*)(wreg + 2880 * KB);    //            /
    __bf16* fc4WT  = (__bf16*)(wreg + 3456 * KB);
    __bf16* semW1T = (__bf16*)(wreg + 4032 * KB);    // [384][384] \ contiguous
    __bf16* depW1T = (__bf16*)(wreg + 4320 * KB);    //            /
    __bf16* fc3WT  = (__bf16*)(wreg + 4608 * KB);
    __bf16* fc1WT  = (__bf16*)(wreg + 4896 * KB);    // [128 pad][384]
    __bf16* fc2WT  = (__bf16*)(wreg + 4992 * KB);    // [384][32]
    float*  bqk    = (float*)(wreg + 5016 * KB);     // [1536]
    float*  sbd0   = (float*)(wreg + 5024 * KB);     // [768] semb0|depb0
    float*  sbd1   = (float*)(wreg + 5028 * KB);     // [768] semb1|depb1
    float*  lossb  = (float*)(wreg + 5036 * KB);     // 64KB

    long nSM = (long)S * Mm, nSS = (long)S * S;
    long nPM = (long)Mm * S;

    // ---- casts ----
    cast_bf16_kernel<<<(MT * D / 4 + 255) / 256, 256, 0, stream>>>(X, Xb, (long)MT * D / 4);
    cast_bf16_kernel<<<((long)B * nSS / 4 + 255) / 256, 256, 0, stream>>>(adjm, adjmb, (long)B * nSS / 4);
    {
        WCast wc;
        const float* srcs[10] = {Wq, Wk, semW0, depW0, fc4W, semW1, depW1, fc3W, fc1W, fc2W};
        unsigned offs[10] = {0u, 589824u, 1179648u, 1474560u, 1769472u,
                             2064384u, 2211840u, 2359296u, 2506752u, 2555904u};
        int Rs[10] = {768, 768, 768, 768, 768, 384, 384, 384, 384, 32};
        int Cs[10] = {768, 768, 384, 384, 384, 384, 384, 384, 32, 384};
        int st = 0;
        for (int i = 0; i < 10; i++) {
            wc.src[i] = srcs[i]; wc.dstOff[i] = offs[i];
            wc.R[i] = Rs[i]; wc.C[i] = Cs[i];
            wc.start[i] = st; st += (Rs[i] / 32) * (Cs[i] / 32);
        }
        wc.start[10] = st;  // 2472
        castW_kernel<<<st, 256, 0, stream>>>(wc, wb);
    }
    hipMemsetAsync(fc1WT + 32 * Mm, 0, (size_t)96 * Mm * 2, stream);
    hipMemcpyAsync(bqk, bq, D * 4, hipMemcpyDeviceToDevice, stream);
    hipMemcpyAsync(bqk + D, bk, D * 4, hipMemcpyDeviceToDevice, stream);
    hipMemcpyAsync(sbd0, semb0, Mm * 4, hipMemcpyDeviceToDevice, stream);
    hipMemcpyAsync(sbd0 + Mm, depb0, Mm * 4, hipMemcpyDeviceToDevice, stream);
    hipMemcpyAsync(sbd1, semb1, Mm * 4, hipMemcpyDeviceToDevice, stream);
    hipMemcpyAsync(sbd1 + Mm, depb1, Mm * 4, hipMemcpyDeviceToDevice, stream);

    // ---- fused q|k projection ----
    mg(stream, Xb, WqkT, bqk, 1, 0, nullptr, nullptr, qkb, MT, 1536, 1536, D,
       D, D, 1536, 0, 0, 0, 0, 1, 0, 1, 0);

    // ---- attention: materialized bf16 scores, 2 chunks of 16 batches ----
    for (int c = 0; c < 2; c++) {
        const __bf16* qc = qkb + (long)c * 16 * S * 1536;
        mg(stream, qc, qc + 768, nullptr, 1, 0, nullptr, nullptr, scoreB, S, S, S, 96,
           1536, 1536, S, (long)S * 1536, 96, (long)S * 1536, 96, 8, nSS, 128, 0);
        softmax_combine<<<dim3(S, 16), 256, 0, stream>>>(scoreB, attn_mask, adj_agb, c * 16);
    }

    long n8 = (long)MT * Mm / 8;
    int cwg = (int)((n8 + 255) / 256);

    // ---- layer 0 ----
    // P64[z<32] = (X_b @ semW0)^T, P64[z>=32] = (X_b @ depW0)^T
    mg(stream, semW0T, Xb, nullptr, 1, 0, nullptr, nullptr, P64, Mm, S, S, D,
       D, D, S, (long)Mm * D, 0, 0, (long)S * D, 32, nPM, 64, 0);
    // merged adjacency: z<32 adj_ag@Psem+semb0 -> Isem; z>=32 adjm@Pdep+depb0 -> Idep (bf16)
    mg(stream, adj_agb, P64, sbd0, 32, Mm, nullptr, nullptr, IsIdb, S, Mm, Mm, S,
       S, S, Mm, 0, nSS, 0, nPM, 64, nSM, 64, 0);
    gcn_combine2<<<cwg, 256, 0, stream>>>(IsIdb, Icomb, n8);
    // Hpre = X @ fc4W + fc4b  (bf16)
    mg(stream, Xb, fc4WT, fc4b, 1, 0, nullptr, nullptr, Hpreb, MT, Mm, Mm, D,
       D, D, Mm, 0, 0, 0, 0, 1, 0, 1, 0);
    // Hb = gate(Hpre, relu(Icom @ fc3W + fc3b))
    mg(stream, Icomb, fc3WT, fc3b, 1, 0, Hpreb, nullptr, Hb, MT, Mm, Mm, Mm,
       Mm, Mm, Mm, 0, 0, 0, 0, 1, 0, 1, 4);

    // ---- layer 1 ----
    mg(stream, semW1T, Hb, nullptr, 1, 0, nullptr, nullptr, P64, Mm, S, S, Mm,
       Mm, Mm, S, (long)Mm * Mm, 0, 0, nSM, 32, nPM, 64, 0);
    mg(stream, adj_agb, P64, sbd1, 32, Mm, nullptr, nullptr, IsIdb, S, Mm, Mm, S,
       S, S, Mm, 0, nSS, 0, nPM, 64, nSM, 64, 0);
    gcn_combine2<<<cwg, 256, 0, stream>>>(IsIdb, Icomb, n8);
    // Hb = gate(Hb, relu(Icom @ fc3W + fc3b))  (in place; per-thread read-then-write)
    mg(stream, Icomb, fc3WT, fc3b, 1, 0, Hb, nullptr, Hb, MT, Mm, Mm, Mm,
       Mm, Mm, Mm, 0, 0, 0, 0, 1, 0, 1, 4);

    // ---- projection heads, z=2 (z0: Hb->h1, z1: Isemb->h2) ----
    long sAproj = (long)(Isemb - Hb);  // constant offset between the two A bases
    mg(stream, Hb, fc1WT, fc1b, 1, 0, nullptr, nullptr, t1b, MT, 128, 32, Mm,
       Mm, Mm, 32, 0, sAproj, 0, 0, 2, (long)MT * 32, 2, 2);
    mg(stream, t1b, fc2WT, fc2b, 1, 0, nullptr, nullptr, hb12, MT, Mm, Mm, 32,
       32, 32, Mm, 0, (long)MT * 32, 0, 0, 2, (long)MT * Mm, 2, 0);

    rownorm<<<2 * MT, 128, 0, stream>>>(hb12, Mm);

    // ---- Gram matrices (bf16): z<32 -> B=h1b, z>=32 -> B=h2b ----
    mg(stream, h1b, h1b, nullptr, 1, 0, nullptr, nullptr, G11, S, S, S, Mm,
       Mm, Mm, S, 0, nSM, 32 * nSM, nSM, 32, nSS, 64, 0);   // G11 | G12
    mg(stream, h2b, h1b, nullptr, 1, 0, nullptr, nullptr, G21, S, S, S, Mm,
       Mm, Mm, S, 0, nSM, 32 * nSM, nSM, 32, nSS, 64, 0);   // G21 | G22

    // ---- loss ----
    loss_kernel<<<dim3(S, B), 256, 0, stream>>>(G11, G12, G21, G22, s_mask, a_mask, lossb);
    final_reduce<<<1, 256, 0, stream>>>(lossb, (float*)d_out, MT);
}